// Round 11
// baseline (998.081 us; speedup 1.0000x reference)
//
#include <hip/hip_runtime.h>
#include <math.h>

#define NB 4
#define NV 8
#define NC 32
#define NG 65536
#define IMGW 256
#define NBI 32               // NB*NV
#define RSPLIT 8             // pixel-range split per (b,i)
#define RBINS (NG / RSPLIT)  // 8192 bins per range
#define START_STRIDE 65544   // 65536 + sentinel + pad
#define SORT_STRIDE (1u << 20) // padded slot capacity per bi
#define SENTINEL (8u << 27)  // widx=8 (w=0); byte-row masks to 0

static constexpr long long STACKED_ELEMS = (long long)NB * NV * NG * NC; // 67108864

// ---------------- ws layout ----------------
// At     : 256 f32                     @ 0
// start  : [bi][65544] u32 (PADDED)    @ 4 KB     (8.39 MB)  8-aligned starts + sentinel
// cnt    : [bi][65536] u32             @ +8.39 MB (8.39 MB)  [reused as wsum after k3]
// pixarr : [bi][j][g] u16              @ +16.8 MB (33.6 MB)
// sorted : [bi][slot] u32 (1<<20 ea)   @ +50.3 MB (134 MB)   payload (j<<27)|(rowidx<<7)
static constexpr size_t OFF_AT    = 0;
static constexpr size_t OFF_START = 4096;
static constexpr size_t OFF_CNT   = OFF_START + (size_t)NBI * START_STRIDE * 4;
static constexpr size_t OFF_PIX   = OFF_CNT + (size_t)NBI * NG * 4;
static constexpr size_t OFF_SORT  = OFF_PIX + (size_t)NBI * NV * NG * 2;

// ---------------- adjacency ----------------
__global__ __launch_bounds__(256) void adj_kernel(const float* __restrict__ ext,
                                                  float* __restrict__ A_out,
                                                  float* __restrict__ At_out)
{
    __shared__ float ctr[NB * NV][3];
    __shared__ float Dsh[NB * NV * NV];
    int t = threadIdx.x;
    if (t < NB * NV) {
        const float* E = ext + t * 16;
        #pragma unroll
        for (int i = 0; i < 3; i++) {
            float s = E[0 * 4 + i] * E[0 * 4 + 3]
                    + E[1 * 4 + i] * E[1 * 4 + 3]
                    + E[2 * 4 + i] * E[2 * 4 + 3];
            ctr[t][i] = -s;
        }
    }
    __syncthreads();
    {
        int b = t >> 6, i = (t >> 3) & 7, j = t & 7;
        float dx = ctr[b * 8 + i][0] - ctr[b * 8 + j][0];
        float dy = ctr[b * 8 + i][1] - ctr[b * 8 + j][1];
        float dz = ctr[b * 8 + i][2] - ctr[b * 8 + j][2];
        Dsh[t] = dx * dx + dy * dy + dz * dz;
    }
    __syncthreads();
    if (t < NB * NV) {
        int ri = t & 7;
        const float* drow = &Dsh[t * 8];
        bool chosen[8] = {false, false, false, false, false, false, false, false};
        for (int n = 0; n < 3; n++) {
            int best = -1; float bs = -3.0e38f;
            for (int j2 = 0; j2 < 8; j2++) {
                if (j2 == ri || chosen[j2]) continue;
                float s = -drow[j2];
                if (s > bs) { bs = s; best = j2; }
            }
            chosen[best] = true;
        }
        float row[8]; float deg = 0.f;
        #pragma unroll
        for (int j2 = 0; j2 < 8; j2++) {
            float a = 0.f;
            if (j2 == ri)        a = 1.0f;
            else if (chosen[j2]) a = 1.0f / (1.0f + sqrtf(drow[j2] + 1e-6f));
            row[j2] = a; deg += a;
        }
        float dn = deg + (deg == 0.f ? 1.f : 0.f);
        #pragma unroll
        for (int j2 = 0; j2 < 8; j2++) {
            A_out[t * 8 + j2]  = row[j2];
            At_out[t * 8 + j2] = row[j2] / dn;
        }
    }
}

// ---------------- k1: pixel precompute (pure streaming, no atomics) ----------------
__global__ __launch_bounds__(256) void k1_pix(const float2* __restrict__ xy,
                                              unsigned short* __restrict__ pixarr)
{
    unsigned int base = blockIdx.x * 1024 + threadIdx.x; // 4 chunks of 256
    #pragma unroll
    for (int k = 0; k < 4; k++) {
        unsigned int tid = base + k * 256; // [b][j][i][g]
        float2 p = xy[tid];
        float px = fminf(fmaxf(rintf(p.x), 0.f), (float)(IMGW - 1));
        float py = fminf(fmaxf(rintf(p.y), 0.f), (float)(IMGW - 1));
        unsigned int pix = (unsigned int)py * IMGW + (unsigned int)px;
        unsigned int g = tid & 0xFFFFu;
        unsigned int i = (tid >> 16) & 7u;
        unsigned int j = (tid >> 19) & 7u;
        unsigned int b = tid >> 22;
        unsigned int bi = (b << 3) | i;
        pixarr[(((bi << 3) | j) << 16) | g] = (unsigned short)pix; // [bi][j][g]
    }
}

// ---------------- k2: LDS histogram per (bi, pixel-range) ----------------
__global__ __launch_bounds__(1024) void k2_hist(const unsigned short* __restrict__ pixarr,
                                                unsigned int* __restrict__ cnt)
{
    __shared__ unsigned int hist[RBINS]; // 32 KB
    int t = threadIdx.x;
    unsigned int bi = blockIdx.x >> 3;
    unsigned int r  = blockIdx.x & 7u;
    unsigned int r0 = r * RBINS;
    for (int k = t; k < RBINS; k += 1024) hist[k] = 0;
    __syncthreads();
    const uint4* src = (const uint4*)(pixarr + ((size_t)bi << 19)); // 64K uint4
    for (int it = 0; it < 64; it++) {
        uint4 v = src[t + it * 1024];
        const unsigned int* vw = (const unsigned int*)&v;
        #pragma unroll
        for (int h = 0; h < 4; h++) {
            unsigned int w = vw[h];
            unsigned int p0 = (w & 0xFFFFu) - r0;
            unsigned int p1 = (w >> 16) - r0;
            if (p0 < RBINS) atomicAdd(&hist[p0], 1u);
            if (p1 < RBINS) atomicAdd(&hist[p1], 1u);
        }
    }
    __syncthreads();
    unsigned int* dst = cnt + ((size_t)bi << 16) + r0;
    for (int k = t; k < RBINS; k += 1024) dst[k] = hist[k];
}

// ---------------- k3: exclusive scan of PADDED counts -> 8-aligned starts ----------------
__global__ __launch_bounds__(1024) void k3_scan(const unsigned int* __restrict__ cnt,
                                                unsigned int* __restrict__ start)
{
    __shared__ unsigned int lds[1024];
    int bi = blockIdx.x;
    const unsigned int* c = cnt + ((size_t)bi << 16);
    unsigned int* st = start + (size_t)bi * START_STRIDE;
    int t = threadIdx.x;
    unsigned int s = 0;
    for (int k = 0; k < 64; k++) s += (c[t * 64 + k] + 7u) & ~7u;
    lds[t] = s;
    __syncthreads();
    for (int off = 1; off < 1024; off <<= 1) {
        unsigned int v = (t >= off) ? lds[t - off] : 0u;
        __syncthreads();
        lds[t] += v;
        __syncthreads();
    }
    unsigned int run = lds[t] - s;
    for (int k = 0; k < 64; k++) {
        unsigned int cv = (c[t * 64 + k] + 7u) & ~7u;
        st[t * 64 + k] = run;
        run += cv;
    }
    if (t == 1023) st[NG] = run; // sentinel
}

// ---------------- k4: counting-sort fill + sentinel padding (LDS cursors) ----------------
// Payload: (j << 27) | (rowidx << 7), rowidx = (j<<16)|g  -> pre-scaled byte offset.
__global__ __launch_bounds__(1024) void k4_fill(const unsigned short* __restrict__ pixarr,
                                                const unsigned int* __restrict__ start,
                                                unsigned int* __restrict__ sorted)
{
    __shared__ unsigned int cur[RBINS]; // 32 KB, init = padded start
    int t = threadIdx.x;
    unsigned int bi = blockIdx.x >> 3;
    unsigned int r  = blockIdx.x & 7u;
    unsigned int r0 = r * RBINS;
    const unsigned int* stg = start + (size_t)bi * START_STRIDE;
    for (int k = t; k < RBINS; k += 1024) cur[k] = stg[r0 + k];
    __syncthreads();
    const uint4* src = (const uint4*)(pixarr + ((size_t)bi << 19));
    unsigned int* dstbase = sorted + (size_t)bi * SORT_STRIDE;
    for (int it = 0; it < 64; it++) {
        unsigned int m0 = (t + it * 1024) * 8;
        uint4 v = src[t + it * 1024];
        const unsigned int* vw = (const unsigned int*)&v;
        #pragma unroll
        for (int h = 0; h < 8; h++) {
            unsigned int w = vw[h >> 1];
            unsigned int pv = ((h & 1) ? (w >> 16) : (w & 0xFFFFu)) - r0;
            if (pv < RBINS) {
                unsigned int slot = atomicAdd(&cur[pv], 1u); // LDS atomic
                unsigned int m = m0 + h;                      // (j<<16)|g
                dstbase[slot] = ((m >> 16) << 27) | (m << 7);
            }
        }
    }
    __syncthreads();
    // pad each bin up to the next bin's (padded) start
    for (int k = t; k < RBINS; k += 1024) {
        unsigned int e = stg[r0 + k + 1];
        for (unsigned int x = cur[k]; x < e; x++) dstbase[x] = SENTINEL;
    }
}

// ---------------- b_gather: slim weighted gather (no epilogue) ----------------
// 32-lane group per output row (b,i,g); lane c owns channel c.
// Per slot: 1 and_or addr, 1 lshr, 1 ds_read, 1 global load, fmac, add.
__global__ __launch_bounds__(256) void b_gather(
    const float* __restrict__ feat,            // raw f32 features (B,V,G,C)
    const unsigned short* __restrict__ pixarr,
    const unsigned int* __restrict__ start,
    const unsigned int* __restrict__ sorted,
    const float* __restrict__ At,
    float* __restrict__ out,                   // raw acc rows (pre-linear)
    float* __restrict__ wsum_g)                // per-row weight sums
{
    __shared__ float At9[NBI][16]; // 9-wide weight rows (index 8 = 0.0)
    int t = threadIdx.x;
    int c = t & 31;

    unsigned int rrow = blockIdx.x * 8 + (t >> 5); // [bi][g]
    unsigned int g = rrow & 0xFFFFu;
    unsigned int bi = rrow >> 16;
    unsigned int i = bi & 7u;
    unsigned int b = bi >> 3;
    unsigned int pix = pixarr[(((bi << 3) | i) << 16) | g]; // diag pixel

    At9[t >> 3][t & 7] = At[t];
    At9[t >> 3][8 + (t & 7)] = 0.f;

    const unsigned int* st = start + (size_t)bi * START_STRIDE;
    unsigned int s0 = st[pix];     // 8-aligned
    unsigned int e0 = st[pix + 1]; // padded end
    const unsigned int* pl = sorted + (size_t)bi * SORT_STRIDE;
    const char* fbB = (const char*)(feat + (((size_t)b) << 19) * NC); // byte base of feat[b]
    unsigned int cb = c << 2;
    __syncthreads();

    const float* Atrow = At9[bi];
    float acc = 0.f, wsum = 0.f;
    for (unsigned int k0 = s0; k0 < e0; k0 += 8) {
        uint4 pa = *(const uint4*)(pl + k0);
        uint4 pb = *(const uint4*)(pl + k0 + 4);
        unsigned int pv[8] = {pa.x, pa.y, pa.z, pa.w, pb.x, pb.y, pb.z, pb.w};
        #pragma unroll
        for (int h = 0; h < 8; h++) {
            unsigned int baddr = (pv[h] & 0x03FFFF80u) | cb;     // byte offset of feat elem
            float fv = *(const float*)(fbB + baddr);             // sentinel -> row 0
            float w = Atrow[pv[h] >> 27];                        // sentinel -> 0.0
            acc = fmaf(w, fv, acc);
            wsum += w;
        }
    }

    out[(((size_t)bi << 16) | g) * NC + c] = acc;
    if (c == 0) wsum_g[rrow] = wsum;
}

// ---------------- kl_lin: in-place 32x32 linear on out + bias*wsum ----------------
// 32-lane group per row; W columns hoisted into VGPRs (grid-stride amortized).
__global__ __launch_bounds__(256) void kl_lin(
    float* __restrict__ out,
    const float* __restrict__ wsum_g,
    const float* __restrict__ Wlin,
    const float* __restrict__ blin)
{
    __shared__ __align__(16) float rowbuf[8][NC];
    int t = threadIdx.x;
    int c = t & 31;
    int grp = t >> 5;
    float wcol[NC];
    #pragma unroll
    for (int k = 0; k < NC; k++) wcol[k] = Wlin[k * NC + c];
    float bias = blin[c];

    const unsigned int totalRows = (unsigned int)(NB * NV * NG); // 2,097,152
    for (unsigned int r0 = blockIdx.x * 8; r0 < totalRows; r0 += gridDim.x * 8) {
        unsigned int r = r0 + grp;
        float v = out[(size_t)r * NC + c];
        float ws = wsum_g[r];
        __syncthreads();
        rowbuf[grp][c] = v;
        __syncthreads();
        float o = bias * ws;
        const float4* rb4 = (const float4*)rowbuf[grp];
        #pragma unroll
        for (int kk = 0; kk < 8; kk++) {
            float4 f4 = rb4[kk];
            o = fmaf(f4.x, wcol[4 * kk + 0], o);
            o = fmaf(f4.y, wcol[4 * kk + 1], o);
            o = fmaf(f4.z, wcol[4 * kk + 2], o);
            o = fmaf(f4.w, wcol[4 * kk + 3], o);
        }
        __builtin_nontemporal_store(o, &out[(size_t)r * NC + c]);
    }
}

extern "C" void kernel_launch(void* const* d_in, const int* in_sizes, int n_in,
                              void* d_out, int out_size, void* d_ws, size_t ws_size,
                              hipStream_t stream)
{
    const float* features = (const float*)d_in[0];
    const float* xy       = (const float*)d_in[1];
    const float* ext      = (const float*)d_in[2];
    const float* Wlin     = (const float*)d_in[3];
    const float* blin     = (const float*)d_in[4];
    float* out = (float*)d_out;

    char* ws = (char*)d_ws;
    float*          At     = (float*)(ws + OFF_AT);
    unsigned int*   start  = (unsigned int*)(ws + OFF_START);
    unsigned int*   cnt    = (unsigned int*)(ws + OFF_CNT);
    unsigned short* pixarr = (unsigned short*)(ws + OFF_PIX);
    unsigned int*   sorted = (unsigned int*)(ws + OFF_SORT);
    float*          wsum_g = (float*)(ws + OFF_CNT); // overlays cnt (dead after k3)

    adj_kernel<<<1, 256, 0, stream>>>(ext, out + STACKED_ELEMS, At);

    k1_pix<<<(NB * NV * NV * NG) / 1024, 256, 0, stream>>>((const float2*)xy, pixarr);
    k2_hist<<<NBI * RSPLIT, 1024, 0, stream>>>(pixarr, cnt);
    k3_scan<<<NBI, 1024, 0, stream>>>(cnt, start);
    k4_fill<<<NBI * RSPLIT, 1024, 0, stream>>>(pixarr, start, sorted);

    const int nrows_blocks = (NB * NV * NG) / 8;
    b_gather<<<nrows_blocks, 256, 0, stream>>>(features, pixarr, start, sorted,
                                               At, out, wsum_g);
    kl_lin<<<8192, 256, 0, stream>>>(out, wsum_g, Wlin, blin);
}

// Round 12
// 978.719 us; speedup vs baseline: 1.0198x; 1.0198x over previous
//
#include <hip/hip_runtime.h>
#include <math.h>

#define NB 4
#define NV 8
#define NC 32
#define NG 65536
#define IMGW 256
#define NBI 32               // NB*NV
#define RSPLIT 8             // pixel-range split per (b,i)
#define RBINS (NG / RSPLIT)  // 8192 bins per range
#define START_STRIDE 65544   // 65536 + sentinel + pad
#define SORT_STRIDE (1u << 20) // padded slot capacity per bi
#define SENTINEL (8u << 27)  // widx=8 (w=0); byte-row masks to 0

static constexpr long long STACKED_ELEMS = (long long)NB * NV * NG * NC; // 67108864

typedef __attribute__((ext_vector_type(8))) short short8;
typedef __attribute__((ext_vector_type(4))) float f32x4;

// ---------------- ws layout ----------------
static constexpr size_t OFF_AT    = 0;
static constexpr size_t OFF_START = 4096;
static constexpr size_t OFF_CNT   = OFF_START + (size_t)NBI * START_STRIDE * 4;
static constexpr size_t OFF_PIX   = OFF_CNT + (size_t)NBI * NG * 4;
static constexpr size_t OFF_SORT  = OFF_PIX + (size_t)NBI * NV * NG * 2;

__device__ __forceinline__ unsigned short f2bf(float f)
{
    unsigned int u = __float_as_uint(f);
    return (unsigned short)((u + 0x7FFFu + ((u >> 16) & 1u)) >> 16);
}

// ---------------- adjacency ----------------
__global__ __launch_bounds__(256) void adj_kernel(const float* __restrict__ ext,
                                                  float* __restrict__ A_out,
                                                  float* __restrict__ At_out)
{
    __shared__ float ctr[NB * NV][3];
    __shared__ float Dsh[NB * NV * NV];
    int t = threadIdx.x;
    if (t < NB * NV) {
        const float* E = ext + t * 16;
        #pragma unroll
        for (int i = 0; i < 3; i++) {
            float s = E[0 * 4 + i] * E[0 * 4 + 3]
                    + E[1 * 4 + i] * E[1 * 4 + 3]
                    + E[2 * 4 + i] * E[2 * 4 + 3];
            ctr[t][i] = -s;
        }
    }
    __syncthreads();
    {
        int b = t >> 6, i = (t >> 3) & 7, j = t & 7;
        float dx = ctr[b * 8 + i][0] - ctr[b * 8 + j][0];
        float dy = ctr[b * 8 + i][1] - ctr[b * 8 + j][1];
        float dz = ctr[b * 8 + i][2] - ctr[b * 8 + j][2];
        Dsh[t] = dx * dx + dy * dy + dz * dz;
    }
    __syncthreads();
    if (t < NB * NV) {
        int ri = t & 7;
        const float* drow = &Dsh[t * 8];
        bool chosen[8] = {false, false, false, false, false, false, false, false};
        for (int n = 0; n < 3; n++) {
            int best = -1; float bs = -3.0e38f;
            for (int j2 = 0; j2 < 8; j2++) {
                if (j2 == ri || chosen[j2]) continue;
                float s = -drow[j2];
                if (s > bs) { bs = s; best = j2; }
            }
            chosen[best] = true;
        }
        float row[8]; float deg = 0.f;
        #pragma unroll
        for (int j2 = 0; j2 < 8; j2++) {
            float a = 0.f;
            if (j2 == ri)        a = 1.0f;
            else if (chosen[j2]) a = 1.0f / (1.0f + sqrtf(drow[j2] + 1e-6f));
            row[j2] = a; deg += a;
        }
        float dn = deg + (deg == 0.f ? 1.f : 0.f);
        #pragma unroll
        for (int j2 = 0; j2 < 8; j2++) {
            A_out[t * 8 + j2]  = row[j2];
            At_out[t * 8 + j2] = row[j2] / dn;
        }
    }
}

// ---------------- k1: pixel precompute ----------------
__global__ __launch_bounds__(256) void k1_pix(const float2* __restrict__ xy,
                                              unsigned short* __restrict__ pixarr)
{
    unsigned int base = blockIdx.x * 1024 + threadIdx.x;
    #pragma unroll
    for (int k = 0; k < 4; k++) {
        unsigned int tid = base + k * 256; // [b][j][i][g]
        float2 p = xy[tid];
        float px = fminf(fmaxf(rintf(p.x), 0.f), (float)(IMGW - 1));
        float py = fminf(fmaxf(rintf(p.y), 0.f), (float)(IMGW - 1));
        unsigned int pix = (unsigned int)py * IMGW + (unsigned int)px;
        unsigned int g = tid & 0xFFFFu;
        unsigned int i = (tid >> 16) & 7u;
        unsigned int j = (tid >> 19) & 7u;
        unsigned int b = tid >> 22;
        unsigned int bi = (b << 3) | i;
        pixarr[(((bi << 3) | j) << 16) | g] = (unsigned short)pix; // [bi][j][g]
    }
}

// ---------------- k2: LDS histogram; XCD-swizzled (all r of a bi on one XCD) ----------------
__global__ __launch_bounds__(1024) void k2_hist(const unsigned short* __restrict__ pixarr,
                                                unsigned int* __restrict__ cnt)
{
    __shared__ unsigned int hist[RBINS]; // 32 KB
    int t = threadIdx.x;
    unsigned int bi = blockIdx.x & 31u;  // XCD = blockIdx%8 = bi%8
    unsigned int r  = blockIdx.x >> 5;
    unsigned int r0 = r * RBINS;
    for (int k = t; k < RBINS; k += 1024) hist[k] = 0;
    __syncthreads();
    const uint4* src = (const uint4*)(pixarr + ((size_t)bi << 19));
    for (int it = 0; it < 64; it++) {
        uint4 v = src[t + it * 1024];
        const unsigned int* vw = (const unsigned int*)&v;
        #pragma unroll
        for (int h = 0; h < 4; h++) {
            unsigned int w = vw[h];
            unsigned int p0 = (w & 0xFFFFu) - r0;
            unsigned int p1 = (w >> 16) - r0;
            if (p0 < RBINS) atomicAdd(&hist[p0], 1u);
            if (p1 < RBINS) atomicAdd(&hist[p1], 1u);
        }
    }
    __syncthreads();
    unsigned int* dst = cnt + ((size_t)bi << 16) + r0;
    for (int k = t; k < RBINS; k += 1024) dst[k] = hist[k];
}

// ---------------- k3: exclusive scan of PADDED counts ----------------
__global__ __launch_bounds__(1024) void k3_scan(const unsigned int* __restrict__ cnt,
                                                unsigned int* __restrict__ start)
{
    __shared__ unsigned int lds[1024];
    int bi = blockIdx.x;
    const unsigned int* c = cnt + ((size_t)bi << 16);
    unsigned int* st = start + (size_t)bi * START_STRIDE;
    int t = threadIdx.x;
    unsigned int s = 0;
    for (int k = 0; k < 64; k++) s += (c[t * 64 + k] + 7u) & ~7u;
    lds[t] = s;
    __syncthreads();
    for (int off = 1; off < 1024; off <<= 1) {
        unsigned int v = (t >= off) ? lds[t - off] : 0u;
        __syncthreads();
        lds[t] += v;
        __syncthreads();
    }
    unsigned int run = lds[t] - s;
    for (int k = 0; k < 64; k++) {
        unsigned int cv = (c[t * 64 + k] + 7u) & ~7u;
        st[t * 64 + k] = run;
        run += cv;
    }
    if (t == 1023) st[NG] = run;
}

// ---------------- k4: counting-sort fill + sentinel padding; XCD-swizzled ----------------
__global__ __launch_bounds__(1024) void k4_fill(const unsigned short* __restrict__ pixarr,
                                                const unsigned int* __restrict__ start,
                                                unsigned int* __restrict__ sorted)
{
    __shared__ unsigned int cur[RBINS]; // 32 KB
    int t = threadIdx.x;
    unsigned int bi = blockIdx.x & 31u;  // XCD = bi%8
    unsigned int r  = blockIdx.x >> 5;
    unsigned int r0 = r * RBINS;
    const unsigned int* stg = start + (size_t)bi * START_STRIDE;
    for (int k = t; k < RBINS; k += 1024) cur[k] = stg[r0 + k];
    __syncthreads();
    const uint4* src = (const uint4*)(pixarr + ((size_t)bi << 19));
    unsigned int* dstbase = sorted + (size_t)bi * SORT_STRIDE;
    for (int it = 0; it < 64; it++) {
        unsigned int m0 = (t + it * 1024) * 8;
        uint4 v = src[t + it * 1024];
        const unsigned int* vw = (const unsigned int*)&v;
        #pragma unroll
        for (int h = 0; h < 8; h++) {
            unsigned int w = vw[h >> 1];
            unsigned int pv = ((h & 1) ? (w >> 16) : (w & 0xFFFFu)) - r0;
            if (pv < RBINS) {
                unsigned int slot = atomicAdd(&cur[pv], 1u);
                unsigned int m = m0 + h;                      // (j<<16)|g
                dstbase[slot] = ((m >> 16) << 27) | (m << 7); // (j<<27)|(rowidx<<7)
            }
        }
    }
    __syncthreads();
    for (int k = t; k < RBINS; k += 1024) {
        unsigned int e = stg[r0 + k + 1];
        for (unsigned int x = cur[k]; x < e; x++) dstbase[x] = SENTINEL;
    }
}

// ---------------- b_gather: gather + fused MFMA linear epilogue ----------------
// 512 threads = 16 groups of 32; group = one output row; lane c = channel.
// Epilogue: acc rows -> LDS -> bf16 A-frags; W as 2 bf16 B-frags; one wave
// does 2x mfma_f32_16x16x32_bf16; C init = bias*wsum; nt-store final out.
__global__ __launch_bounds__(512) void b_gather(
    const float* __restrict__ feat,
    const unsigned short* __restrict__ pixarr,
    const unsigned int* __restrict__ start,
    const unsigned int* __restrict__ sorted,
    const float* __restrict__ Wlin,
    const float* __restrict__ blin,
    const float* __restrict__ At,
    float* __restrict__ out)
{
    __shared__ float At9[NBI][16];     // 9-wide weight rows (index 8 = 0.0)
    __shared__ float accLDS[16][32];
    __shared__ float wsumLDS[16];
    int t = threadIdx.x;
    int c = t & 31;
    int grp = t >> 5;                  // 0..15

    unsigned int rrow = blockIdx.x * 16 + grp; // [bi][g]
    unsigned int g = rrow & 0xFFFFu;
    unsigned int bi = rrow >> 16;      // uniform per block (16-row blocks don't cross bi)
    unsigned int i = bi & 7u;
    unsigned int b = bi >> 3;
    unsigned int pix = pixarr[(((bi << 3) | i) << 16) | g];

    if (t < 256) { At9[t >> 3][t & 7] = At[t]; }
    else { int u = t - 256; At9[u >> 3][8 + (u & 7)] = 0.f; }

    // preload W fragments (uniform across blocks -> L2-hot). lane l of wave0
    // would need them, but load in all lanes (cheap, avoids divergence).
    int l = t & 63;
    short8 bf0, bf1;
    #pragma unroll
    for (int j = 0; j < 8; j++) {
        int kk = (l >> 4) * 8 + j;
        bf0[j] = (short)f2bf(Wlin[kk * NC + (l & 15)]);
        bf1[j] = (short)f2bf(Wlin[kk * NC + 16 + (l & 15)]);
    }

    const unsigned int* st = start + (size_t)bi * START_STRIDE;
    unsigned int s0 = st[pix];
    unsigned int e0 = st[pix + 1];
    const unsigned int* pl = sorted + (size_t)bi * SORT_STRIDE;
    const char* fbB = (const char*)(feat + (((size_t)b) << 19) * NC);
    unsigned int cb = c << 2;
    __syncthreads();

    const float* Atrow = At9[bi];
    float acc = 0.f, wsum = 0.f;
    for (unsigned int k0 = s0; k0 < e0; k0 += 8) {
        uint4 pa = *(const uint4*)(pl + k0);
        uint4 pb = *(const uint4*)(pl + k0 + 4);
        unsigned int pv[8] = {pa.x, pa.y, pa.z, pa.w, pb.x, pb.y, pb.z, pb.w};
        #pragma unroll
        for (int h = 0; h < 8; h++) {
            unsigned int baddr = (pv[h] & 0x03FFFF80u) | cb;
            float fv = *(const float*)(fbB + baddr);   // sentinel -> row 0
            float w = Atrow[pv[h] >> 27];              // sentinel -> 0.0
            acc = fmaf(w, fv, acc);
            wsum += w;
        }
    }

    accLDS[grp][c] = acc;
    if (c == 0) wsumLDS[grp] = wsum;
    __syncthreads();

    if (t < 64) {
        // A-frag: row = l&15, k = (l>>4)*8 + j  (same k-map as B -> perm-immune)
        short8 af;
        #pragma unroll
        for (int j = 0; j < 8; j++)
            af[j] = (short)f2bf(accLDS[l & 15][(l >> 4) * 8 + j]);
        float bias0 = blin[l & 15];
        float bias1 = blin[16 + (l & 15)];
        f32x4 c0, c1;
        #pragma unroll
        for (int q = 0; q < 4; q++) {
            float wsr = wsumLDS[(l >> 4) * 4 + q];
            c0[q] = bias0 * wsr;
            c1[q] = bias1 * wsr;
        }
        c0 = __builtin_amdgcn_mfma_f32_16x16x32_bf16(af, bf0, c0, 0, 0, 0);
        c1 = __builtin_amdgcn_mfma_f32_16x16x32_bf16(af, bf1, c1, 0, 0, 0);
        size_t rowbase = (size_t)blockIdx.x * 16;
        #pragma unroll
        for (int q = 0; q < 4; q++) {
            size_t r = rowbase + (l >> 4) * 4 + q;
            __builtin_nontemporal_store(c0[q], &out[r * NC + (l & 15)]);
            __builtin_nontemporal_store(c1[q], &out[r * NC + 16 + (l & 15)]);
        }
    }
}

extern "C" void kernel_launch(void* const* d_in, const int* in_sizes, int n_in,
                              void* d_out, int out_size, void* d_ws, size_t ws_size,
                              hipStream_t stream)
{
    const float* features = (const float*)d_in[0];
    const float* xy       = (const float*)d_in[1];
    const float* ext      = (const float*)d_in[2];
    const float* Wlin     = (const float*)d_in[3];
    const float* blin     = (const float*)d_in[4];
    float* out = (float*)d_out;

    char* ws = (char*)d_ws;
    float*          At     = (float*)(ws + OFF_AT);
    unsigned int*   start  = (unsigned int*)(ws + OFF_START);
    unsigned int*   cnt    = (unsigned int*)(ws + OFF_CNT);
    unsigned short* pixarr = (unsigned short*)(ws + OFF_PIX);
    unsigned int*   sorted = (unsigned int*)(ws + OFF_SORT);

    adj_kernel<<<1, 256, 0, stream>>>(ext, out + STACKED_ELEMS, At);

    k1_pix<<<(NB * NV * NV * NG) / 1024, 256, 0, stream>>>((const float2*)xy, pixarr);
    k2_hist<<<NBI * RSPLIT, 1024, 0, stream>>>(pixarr, cnt);
    k3_scan<<<NBI, 1024, 0, stream>>>(cnt, start);
    k4_fill<<<NBI * RSPLIT, 1024, 0, stream>>>(pixarr, start, sorted);

    const int nrows_blocks = (NB * NV * NG) / 16; // 131072 blocks x 16 rows
    b_gather<<<nrows_blocks, 512, 0, stream>>>(features, pixarr, start, sorted,
                                               Wlin, blin, At, out);
}

// Round 16
// 920.067 us; speedup vs baseline: 1.0848x; 1.0637x over previous
//
#include <hip/hip_runtime.h>
#include <math.h>

#define NB 4
#define NV 8
#define NC 32
#define NG 65536
#define IMGW 256
#define NBI 32               // NB*NV
#define RSPLIT 8             // pixel-range split per (b,i)
#define RBINS (NG / RSPLIT)  // 8192 bins per range
#define START_STRIDE 65544   // 65536 + sentinel + pad
#define SORT_STRIDE (1u << 20) // padded slot capacity per bi
#define SENTINEL (8u << 27)  // widx=8 (w=0); byte-row masks to 0

static constexpr long long STACKED_ELEMS = (long long)NB * NV * NG * NC; // 67108864

typedef __attribute__((ext_vector_type(8))) short short8;
typedef __attribute__((ext_vector_type(4))) float f32x4;

// ---------------- ws layout ----------------
static constexpr size_t OFF_AT    = 0;
static constexpr size_t OFF_START = 4096;
static constexpr size_t OFF_CNT   = OFF_START + (size_t)NBI * START_STRIDE * 4;
static constexpr size_t OFF_PIX   = OFF_CNT + (size_t)NBI * NG * 4;
static constexpr size_t OFF_SORT  = OFF_PIX + (size_t)NBI * NV * NG * 2;

__device__ __forceinline__ unsigned short f2bf(float f)
{
    unsigned int u = __float_as_uint(f);
    return (unsigned short)((u + 0x7FFFu + ((u >> 16) & 1u)) >> 16);
}

// ---------------- adjacency ----------------
__global__ __launch_bounds__(256) void adj_kernel(const float* __restrict__ ext,
                                                  float* __restrict__ A_out,
                                                  float* __restrict__ At_out)
{
    __shared__ float ctr[NB * NV][3];
    __shared__ float Dsh[NB * NV * NV];
    int t = threadIdx.x;
    if (t < NB * NV) {
        const float* E = ext + t * 16;
        #pragma unroll
        for (int i = 0; i < 3; i++) {
            float s = E[0 * 4 + i] * E[0 * 4 + 3]
                    + E[1 * 4 + i] * E[1 * 4 + 3]
                    + E[2 * 4 + i] * E[2 * 4 + 3];
            ctr[t][i] = -s;
        }
    }
    __syncthreads();
    {
        int b = t >> 6, i = (t >> 3) & 7, j = t & 7;
        float dx = ctr[b * 8 + i][0] - ctr[b * 8 + j][0];
        float dy = ctr[b * 8 + i][1] - ctr[b * 8 + j][1];
        float dz = ctr[b * 8 + i][2] - ctr[b * 8 + j][2];
        Dsh[t] = dx * dx + dy * dy + dz * dz;
    }
    __syncthreads();
    if (t < NB * NV) {
        int ri = t & 7;
        const float* drow = &Dsh[t * 8];
        bool chosen[8] = {false, false, false, false, false, false, false, false};
        for (int n = 0; n < 3; n++) {
            int best = -1; float bs = -3.0e38f;
            for (int j2 = 0; j2 < 8; j2++) {
                if (j2 == ri || chosen[j2]) continue;
                float s = -drow[j2];
                if (s > bs) { bs = s; best = j2; }
            }
            chosen[best] = true;
        }
        float row[8]; float deg = 0.f;
        #pragma unroll
        for (int j2 = 0; j2 < 8; j2++) {
            float a = 0.f;
            if (j2 == ri)        a = 1.0f;
            else if (chosen[j2]) a = 1.0f / (1.0f + sqrtf(drow[j2] + 1e-6f));
            row[j2] = a; deg += a;
        }
        float dn = deg + (deg == 0.f ? 1.f : 0.f);
        #pragma unroll
        for (int j2 = 0; j2 < 8; j2++) {
            A_out[t * 8 + j2]  = row[j2];
            At_out[t * 8 + j2] = row[j2] / dn;
        }
    }
}

// ---------------- k1: pixel precompute ----------------
__global__ __launch_bounds__(256) void k1_pix(const float2* __restrict__ xy,
                                              unsigned short* __restrict__ pixarr)
{
    unsigned int base = blockIdx.x * 1024 + threadIdx.x;
    #pragma unroll
    for (int k = 0; k < 4; k++) {
        unsigned int tid = base + k * 256; // [b][j][i][g]
        float2 p = xy[tid];
        float px = fminf(fmaxf(rintf(p.x), 0.f), (float)(IMGW - 1));
        float py = fminf(fmaxf(rintf(p.y), 0.f), (float)(IMGW - 1));
        unsigned int pix = (unsigned int)py * IMGW + (unsigned int)px;
        unsigned int g = tid & 0xFFFFu;
        unsigned int i = (tid >> 16) & 7u;
        unsigned int j = (tid >> 19) & 7u;
        unsigned int b = tid >> 22;
        unsigned int bi = (b << 3) | i;
        pixarr[(((bi << 3) | j) << 16) | g] = (unsigned short)pix; // [bi][j][g]
    }
}

// ---------------- k2: LDS histogram; XCD-swizzled; 4x batched loads ----------------
__global__ __launch_bounds__(1024) void k2_hist(const unsigned short* __restrict__ pixarr,
                                                unsigned int* __restrict__ cnt)
{
    __shared__ unsigned int hist[RBINS]; // 32 KB
    int t = threadIdx.x;
    unsigned int bi = blockIdx.x & 31u;  // XCD = bi%8
    unsigned int r  = blockIdx.x >> 5;
    unsigned int r0 = r * RBINS;
    for (int k = t; k < RBINS; k += 1024) hist[k] = 0;
    __syncthreads();
    const uint4* src = (const uint4*)(pixarr + ((size_t)bi << 19));
    for (int it = 0; it < 16; it++) {
        uint4 vv[4];
        #pragma unroll
        for (int q = 0; q < 4; q++)
            vv[q] = src[t + (it * 4 + q) * 1024]; // 4 independent loads in flight
        #pragma unroll
        for (int q = 0; q < 4; q++) {
            const unsigned int* vw = (const unsigned int*)&vv[q];
            #pragma unroll
            for (int h = 0; h < 4; h++) {
                unsigned int w = vw[h];
                unsigned int p0 = (w & 0xFFFFu) - r0;
                unsigned int p1 = (w >> 16) - r0;
                if (p0 < RBINS) atomicAdd(&hist[p0], 1u);
                if (p1 < RBINS) atomicAdd(&hist[p1], 1u);
            }
        }
    }
    __syncthreads();
    unsigned int* dst = cnt + ((size_t)bi << 16) + r0;
    for (int k = t; k < RBINS; k += 1024) dst[k] = hist[k];
}

// ---------------- k3: exclusive scan of PADDED counts ----------------
__global__ __launch_bounds__(1024) void k3_scan(const unsigned int* __restrict__ cnt,
                                                unsigned int* __restrict__ start)
{
    __shared__ unsigned int lds[1024];
    int bi = blockIdx.x;
    const unsigned int* c = cnt + ((size_t)bi << 16);
    unsigned int* st = start + (size_t)bi * START_STRIDE;
    int t = threadIdx.x;
    unsigned int s = 0;
    for (int k = 0; k < 64; k++) s += (c[t * 64 + k] + 7u) & ~7u;
    lds[t] = s;
    __syncthreads();
    for (int off = 1; off < 1024; off <<= 1) {
        unsigned int v = (t >= off) ? lds[t - off] : 0u;
        __syncthreads();
        lds[t] += v;
        __syncthreads();
    }
    unsigned int run = lds[t] - s;
    for (int k = 0; k < 64; k++) {
        unsigned int cv = (c[t * 64 + k] + 7u) & ~7u;
        st[t * 64 + k] = run;
        run += cv;
    }
    if (t == 1023) st[NG] = run;
}

// ---------------- k4: counting-sort fill + sentinel padding; 4x batched loads ----------------
__global__ __launch_bounds__(1024) void k4_fill(const unsigned short* __restrict__ pixarr,
                                                const unsigned int* __restrict__ start,
                                                unsigned int* __restrict__ sorted)
{
    __shared__ unsigned int cur[RBINS]; // 32 KB
    int t = threadIdx.x;
    unsigned int bi = blockIdx.x & 31u;  // XCD = bi%8
    unsigned int r  = blockIdx.x >> 5;
    unsigned int r0 = r * RBINS;
    const unsigned int* stg = start + (size_t)bi * START_STRIDE;
    for (int k = t; k < RBINS; k += 1024) cur[k] = stg[r0 + k];
    __syncthreads();
    const uint4* src = (const uint4*)(pixarr + ((size_t)bi << 19));
    unsigned int* dstbase = sorted + (size_t)bi * SORT_STRIDE;
    for (int it = 0; it < 16; it++) {
        uint4 vv[4];
        #pragma unroll
        for (int q = 0; q < 4; q++)
            vv[q] = src[t + (it * 4 + q) * 1024];
        #pragma unroll
        for (int q = 0; q < 4; q++) {
            unsigned int m0 = (t + (it * 4 + q) * 1024) * 8;
            const unsigned int* vw = (const unsigned int*)&vv[q];
            #pragma unroll
            for (int h = 0; h < 8; h++) {
                unsigned int w = vw[h >> 1];
                unsigned int pv = ((h & 1) ? (w >> 16) : (w & 0xFFFFu)) - r0;
                if (pv < RBINS) {
                    unsigned int slot = atomicAdd(&cur[pv], 1u);
                    unsigned int m = m0 + h;                      // (j<<16)|g
                    dstbase[slot] = ((m >> 16) << 27) | (m << 7); // (j<<27)|(rowidx<<7)
                }
            }
        }
    }
    __syncthreads();
    for (int k = t; k < RBINS; k += 1024) {
        unsigned int e = stg[r0 + k + 1];
        for (unsigned int x = cur[k]; x < e; x++) dstbase[x] = SENTINEL;
    }
}

// ---------------- b_gather: gather + WAVE-LOCAL MFMA linear epilogue ----------------
// 256 threads = 8 groups of 32 = 4 waves; each wave owns 2 output rows.
// Epilogue per wave: shfl acc -> bf16 A-frag rows 0-1 (rows 2-15 zero),
// 2x mfma_f32_16x16x32_bf16 vs preloaded W frags; C init = bias*wsum.
// No barriers after the gather loop -> round-11 occupancy preserved.
__global__ __launch_bounds__(256) void b_gather(
    const float* __restrict__ feat,
    const unsigned short* __restrict__ pixarr,
    const unsigned int* __restrict__ start,
    const unsigned int* __restrict__ sorted,
    const float* __restrict__ Wlin,
    const float* __restrict__ blin,
    const float* __restrict__ At,
    float* __restrict__ out)
{
    __shared__ float At9[NBI][16];     // 9-wide weight rows (index 8 = 0.0)
    int t = threadIdx.x;
    int c = t & 31;

    unsigned int rrow = blockIdx.x * 8 + (t >> 5); // [bi][g]
    unsigned int g = rrow & 0xFFFFu;
    unsigned int bi = rrow >> 16;      // uniform per block
    unsigned int i = bi & 7u;
    unsigned int b = bi >> 3;
    unsigned int pix = pixarr[(((bi << 3) | i) << 16) | g];

    At9[t >> 3][t & 7] = At[t];
    At9[t >> 3][8 + (t & 7)] = 0.f;

    // preload W fragments (L2-hot, uniform)
    int l = t & 63;
    short8 bf0, bf1;
    #pragma unroll
    for (int j = 0; j < 8; j++) {
        int kk = (l >> 4) * 8 + j;
        bf0[j] = (short)f2bf(Wlin[kk * NC + (l & 15)]);
        bf1[j] = (short)f2bf(Wlin[kk * NC + 16 + (l & 15)]);
    }

    const unsigned int* st = start + (size_t)bi * START_STRIDE;
    unsigned int s0 = st[pix];
    unsigned int e0 = st[pix + 1];
    const unsigned int* pl = sorted + (size_t)bi * SORT_STRIDE;
    const char* fbB = (const char*)(feat + (((size_t)b) << 19) * NC);
    unsigned int cb = c << 2;
    __syncthreads();

    const float* Atrow = At9[bi];
    float acc = 0.f, wsum = 0.f;
    for (unsigned int k0 = s0; k0 < e0; k0 += 8) {
        uint4 pa = *(const uint4*)(pl + k0);
        uint4 pb = *(const uint4*)(pl + k0 + 4);
        unsigned int pv[8] = {pa.x, pa.y, pa.z, pa.w, pb.x, pb.y, pb.z, pb.w};
        #pragma unroll
        for (int h = 0; h < 8; h++) {
            unsigned int baddr = (pv[h] & 0x03FFFF80u) | cb;
            float fv = *(const float*)(fbB + baddr);   // sentinel -> row 0
            float w = Atrow[pv[h] >> 27];              // sentinel -> 0.0
            acc = fmaf(w, fv, acc);
            wsum += w;
        }
    }

    // ---- wave-local MFMA epilogue (no LDS, no barrier) ----
    // A-frag: row r = l&15 (only r<2 valid), k = (l>>4)*8+j; source lane (r<<5)|k.
    short8 af;
    int r = l & 15;
    #pragma unroll
    for (int j = 0; j < 8; j++) {
        float v = __shfl(acc, ((r & 1) << 5) | ((l >> 4) * 8 + j), 64);
        af[j] = (r < 2) ? (short)f2bf(v) : (short)0;
    }
    float wsr0 = __shfl(wsum, 0, 64);   // row 0 weight-sum (uniform in group 0)
    float wsr1 = __shfl(wsum, 32, 64);  // row 1
    float bias0 = blin[l & 15];
    float bias1 = blin[16 + (l & 15)];
    f32x4 c0, c1;
    #pragma unroll
    for (int q = 0; q < 4; q++) {
        int row = (l >> 4) * 4 + q;      // only rows 0,1 stored
        float wsr = (row == 1) ? wsr1 : wsr0;
        c0[q] = bias0 * wsr;
        c1[q] = bias1 * wsr;
    }
    c0 = __builtin_amdgcn_mfma_f32_16x16x32_bf16(af, bf0, c0, 0, 0, 0);
    c1 = __builtin_amdgcn_mfma_f32_16x16x32_bf16(af, bf1, c1, 0, 0, 0);
    if (l < 16) {
        size_t r0w = (size_t)blockIdx.x * 8 + (t >> 6) * 2; // wave's first row
        __builtin_nontemporal_store(c0[0], &out[(r0w + 0) * NC + l]);
        __builtin_nontemporal_store(c1[0], &out[(r0w + 0) * NC + 16 + l]);
        __builtin_nontemporal_store(c0[1], &out[(r0w + 1) * NC + l]);
        __builtin_nontemporal_store(c1[1], &out[(r0w + 1) * NC + 16 + l]);
    }
}

extern "C" void kernel_launch(void* const* d_in, const int* in_sizes, int n_in,
                              void* d_out, int out_size, void* d_ws, size_t ws_size,
                              hipStream_t stream)
{
    const float* features = (const float*)d_in[0];
    const float* xy       = (const float*)d_in[1];
    const float* ext      = (const float*)d_in[2];
    const float* Wlin     = (const float*)d_in[3];
    const float* blin     = (const float*)d_in[4];
    float* out = (float*)d_out;

    char* ws = (char*)d_ws;
    float*          At     = (float*)(ws + OFF_AT);
    unsigned int*   start  = (unsigned int*)(ws + OFF_START);
    unsigned int*   cnt    = (unsigned int*)(ws + OFF_CNT);
    unsigned short* pixarr = (unsigned short*)(ws + OFF_PIX);
    unsigned int*   sorted = (unsigned int*)(ws + OFF_SORT);

    adj_kernel<<<1, 256, 0, stream>>>(ext, out + STACKED_ELEMS, At);

    k1_pix<<<(NB * NV * NV * NG) / 1024, 256, 0, stream>>>((const float2*)xy, pixarr);
    k2_hist<<<NBI * RSPLIT, 1024, 0, stream>>>(pixarr, cnt);
    k3_scan<<<NBI, 1024, 0, stream>>>(cnt, start);
    k4_fill<<<NBI * RSPLIT, 1024, 0, stream>>>(pixarr, start, sorted);

    const int nrows_blocks = (NB * NV * NG) / 8; // 262144 blocks x 8 rows
    b_gather<<<nrows_blocks, 256, 0, stream>>>(features, pixarr, start, sorted,
                                               Wlin, blin, At, out);
}

// Round 17
// 853.947 us; speedup vs baseline: 1.1688x; 1.0774x over previous
//
#include <hip/hip_runtime.h>
#include <math.h>

#define NB 4
#define NV 8
#define NC 32
#define NG 65536
#define IMGW 256
#define NBI 32               // NB*NV
#define RSPLIT 8             // pixel-range split per (b,i)
#define RBINS (NG / RSPLIT)  // 8192 bins per range
#define START_STRIDE 65544   // 65536 + sentinel + pad
#define SORT_STRIDE (1u << 20) // padded slot capacity per bi
#define SENTINEL (8u << 27)  // widx=8 (w=0); byte-row masks to 0

static constexpr long long STACKED_ELEMS = (long long)NB * NV * NG * NC; // 67108864

typedef __attribute__((ext_vector_type(8))) short short8;
typedef __attribute__((ext_vector_type(4))) float f32x4;

// ---------------- ws layout ----------------
static constexpr size_t OFF_AT    = 0;
static constexpr size_t OFF_START = 4096;
static constexpr size_t OFF_CNT   = OFF_START + (size_t)NBI * START_STRIDE * 4;
static constexpr size_t OFF_PIX   = OFF_CNT + (size_t)NBI * NG * 4;
static constexpr size_t OFF_SORT  = OFF_PIX + (size_t)NBI * NV * NG * 2;

__device__ __forceinline__ unsigned short f2bf(float f)
{
    unsigned int u = __float_as_uint(f);
    return (unsigned short)((u + 0x7FFFu + ((u >> 16) & 1u)) >> 16);
}

// ---------------- adjacency ----------------
__global__ __launch_bounds__(256) void adj_kernel(const float* __restrict__ ext,
                                                  float* __restrict__ A_out,
                                                  float* __restrict__ At_out)
{
    __shared__ float ctr[NB * NV][3];
    __shared__ float Dsh[NB * NV * NV];
    int t = threadIdx.x;
    if (t < NB * NV) {
        const float* E = ext + t * 16;
        #pragma unroll
        for (int i = 0; i < 3; i++) {
            float s = E[0 * 4 + i] * E[0 * 4 + 3]
                    + E[1 * 4 + i] * E[1 * 4 + 3]
                    + E[2 * 4 + i] * E[2 * 4 + 3];
            ctr[t][i] = -s;
        }
    }
    __syncthreads();
    {
        int b = t >> 6, i = (t >> 3) & 7, j = t & 7;
        float dx = ctr[b * 8 + i][0] - ctr[b * 8 + j][0];
        float dy = ctr[b * 8 + i][1] - ctr[b * 8 + j][1];
        float dz = ctr[b * 8 + i][2] - ctr[b * 8 + j][2];
        Dsh[t] = dx * dx + dy * dy + dz * dz;
    }
    __syncthreads();
    if (t < NB * NV) {
        int ri = t & 7;
        const float* drow = &Dsh[t * 8];
        bool chosen[8] = {false, false, false, false, false, false, false, false};
        for (int n = 0; n < 3; n++) {
            int best = -1; float bs = -3.0e38f;
            for (int j2 = 0; j2 < 8; j2++) {
                if (j2 == ri || chosen[j2]) continue;
                float s = -drow[j2];
                if (s > bs) { bs = s; best = j2; }
            }
            chosen[best] = true;
        }
        float row[8]; float deg = 0.f;
        #pragma unroll
        for (int j2 = 0; j2 < 8; j2++) {
            float a = 0.f;
            if (j2 == ri)        a = 1.0f;
            else if (chosen[j2]) a = 1.0f / (1.0f + sqrtf(drow[j2] + 1e-6f));
            row[j2] = a; deg += a;
        }
        float dn = deg + (deg == 0.f ? 1.f : 0.f);
        #pragma unroll
        for (int j2 = 0; j2 < 8; j2++) {
            A_out[t * 8 + j2]  = row[j2];
            At_out[t * 8 + j2] = row[j2] / dn;
        }
    }
}

// ---------------- k1: pixel precompute ----------------
__global__ __launch_bounds__(256) void k1_pix(const float2* __restrict__ xy,
                                              unsigned short* __restrict__ pixarr)
{
    unsigned int base = blockIdx.x * 1024 + threadIdx.x;
    #pragma unroll
    for (int k = 0; k < 4; k++) {
        unsigned int tid = base + k * 256; // [b][j][i][g]
        float2 p = xy[tid];
        float px = fminf(fmaxf(rintf(p.x), 0.f), (float)(IMGW - 1));
        float py = fminf(fmaxf(rintf(p.y), 0.f), (float)(IMGW - 1));
        unsigned int pix = (unsigned int)py * IMGW + (unsigned int)px;
        unsigned int g = tid & 0xFFFFu;
        unsigned int i = (tid >> 16) & 7u;
        unsigned int j = (tid >> 19) & 7u;
        unsigned int b = tid >> 22;
        unsigned int bi = (b << 3) | i;
        pixarr[(((bi << 3) | j) << 16) | g] = (unsigned short)pix; // [bi][j][g]
    }
}

// ---------------- k2: LDS histogram; XCD-swizzled; 4x batched loads ----------------
__global__ __launch_bounds__(1024) void k2_hist(const unsigned short* __restrict__ pixarr,
                                                unsigned int* __restrict__ cnt)
{
    __shared__ unsigned int hist[RBINS]; // 32 KB
    int t = threadIdx.x;
    unsigned int bi = blockIdx.x & 31u;  // XCD = bi%8
    unsigned int r  = blockIdx.x >> 5;
    unsigned int r0 = r * RBINS;
    for (int k = t; k < RBINS; k += 1024) hist[k] = 0;
    __syncthreads();
    const uint4* src = (const uint4*)(pixarr + ((size_t)bi << 19));
    for (int it = 0; it < 16; it++) {
        uint4 vv[4];
        #pragma unroll
        for (int q = 0; q < 4; q++)
            vv[q] = src[t + (it * 4 + q) * 1024]; // 4 independent loads in flight
        #pragma unroll
        for (int q = 0; q < 4; q++) {
            const unsigned int* vw = (const unsigned int*)&vv[q];
            #pragma unroll
            for (int h = 0; h < 4; h++) {
                unsigned int w = vw[h];
                unsigned int p0 = (w & 0xFFFFu) - r0;
                unsigned int p1 = (w >> 16) - r0;
                if (p0 < RBINS) atomicAdd(&hist[p0], 1u);
                if (p1 < RBINS) atomicAdd(&hist[p1], 1u);
            }
        }
    }
    __syncthreads();
    unsigned int* dst = cnt + ((size_t)bi << 16) + r0;
    for (int k = t; k < RBINS; k += 1024) dst[k] = hist[k];
}

// ---------------- k3: exclusive scan of PADDED counts ----------------
__global__ __launch_bounds__(1024) void k3_scan(const unsigned int* __restrict__ cnt,
                                                unsigned int* __restrict__ start)
{
    __shared__ unsigned int lds[1024];
    int bi = blockIdx.x;
    const unsigned int* c = cnt + ((size_t)bi << 16);
    unsigned int* st = start + (size_t)bi * START_STRIDE;
    int t = threadIdx.x;
    unsigned int s = 0;
    for (int k = 0; k < 64; k++) s += (c[t * 64 + k] + 7u) & ~7u;
    lds[t] = s;
    __syncthreads();
    for (int off = 1; off < 1024; off <<= 1) {
        unsigned int v = (t >= off) ? lds[t - off] : 0u;
        __syncthreads();
        lds[t] += v;
        __syncthreads();
    }
    unsigned int run = lds[t] - s;
    for (int k = 0; k < 64; k++) {
        unsigned int cv = (c[t * 64 + k] + 7u) & ~7u;
        st[t * 64 + k] = run;
        run += cv;
    }
    if (t == 1023) st[NG] = run;
}

// ---------------- k4: counting-sort fill + sentinel padding; 4x batched loads ----------------
__global__ __launch_bounds__(1024) void k4_fill(const unsigned short* __restrict__ pixarr,
                                                const unsigned int* __restrict__ start,
                                                unsigned int* __restrict__ sorted)
{
    __shared__ unsigned int cur[RBINS]; // 32 KB
    int t = threadIdx.x;
    unsigned int bi = blockIdx.x & 31u;  // XCD = bi%8
    unsigned int r  = blockIdx.x >> 5;
    unsigned int r0 = r * RBINS;
    const unsigned int* stg = start + (size_t)bi * START_STRIDE;
    for (int k = t; k < RBINS; k += 1024) cur[k] = stg[r0 + k];
    __syncthreads();
    const uint4* src = (const uint4*)(pixarr + ((size_t)bi << 19));
    unsigned int* dstbase = sorted + (size_t)bi * SORT_STRIDE;
    for (int it = 0; it < 16; it++) {
        uint4 vv[4];
        #pragma unroll
        for (int q = 0; q < 4; q++)
            vv[q] = src[t + (it * 4 + q) * 1024];
        #pragma unroll
        for (int q = 0; q < 4; q++) {
            unsigned int m0 = (t + (it * 4 + q) * 1024) * 8;
            const unsigned int* vw = (const unsigned int*)&vv[q];
            #pragma unroll
            for (int h = 0; h < 8; h++) {
                unsigned int w = vw[h >> 1];
                unsigned int pv = ((h & 1) ? (w >> 16) : (w & 0xFFFFu)) - r0;
                if (pv < RBINS) {
                    unsigned int slot = atomicAdd(&cur[pv], 1u);
                    unsigned int m = m0 + h;                      // (j<<16)|g
                    dstbase[slot] = ((m >> 16) << 27) | (m << 7); // (j<<27)|(rowidx<<7)
                }
            }
        }
    }
    __syncthreads();
    for (int k = t; k < RBINS; k += 1024) {
        unsigned int e = stg[r0 + k + 1];
        for (unsigned int x = cur[k]; x < e; x++) dstbase[x] = SENTINEL;
    }
}

// ---------------- b_gather: 2-channel lanes (16/row) + wave-local MFMA epilogue ----------------
// 256 threads = 16 groups of 16; group = one output row; lane owns channels (2c,2c+1).
// Wave = 4 rows. Epilogue: A-frag rows 0-3 via shfl (x/y by j&1), rows 4-15 zero;
// 2x mfma_f32_16x16x32_bf16; C init = bias*wsum on kb==0 quadrant; store rows via lanes<16.
__global__ __launch_bounds__(256) void b_gather(
    const float* __restrict__ feat,
    const unsigned short* __restrict__ pixarr,
    const unsigned int* __restrict__ start,
    const unsigned int* __restrict__ sorted,
    const float* __restrict__ Wlin,
    const float* __restrict__ blin,
    const float* __restrict__ At,
    float* __restrict__ out)
{
    __shared__ float At9[NBI][16];     // 9-wide weight rows (index 8 = 0.0)
    int t = threadIdx.x;
    int c2 = t & 15;                   // channel pair index
    int grp = t >> 4;                  // 0..15 = row within block

    unsigned int rrow = blockIdx.x * 16 + grp; // [bi][g]
    unsigned int g = rrow & 0xFFFFu;
    unsigned int bi = rrow >> 16;      // uniform per block (4096 blocks per bi)
    unsigned int i = bi & 7u;
    unsigned int b = bi >> 3;
    unsigned int pix = pixarr[(((bi << 3) | i) << 16) | g];

    // full init (both halves) - do not rely on LDS zeroing
    At9[t >> 3][t & 7] = At[t];
    At9[t >> 3][8 + (t & 7)] = 0.f;

    // preload W fragments (L2-hot, uniform)
    int l = t & 63;
    short8 bf0, bf1;
    #pragma unroll
    for (int j = 0; j < 8; j++) {
        int kk = (l >> 4) * 8 + j;
        bf0[j] = (short)f2bf(Wlin[kk * NC + (l & 15)]);
        bf1[j] = (short)f2bf(Wlin[kk * NC + 16 + (l & 15)]);
    }

    const unsigned int* st = start + (size_t)bi * START_STRIDE;
    unsigned int s0 = st[pix];
    unsigned int e0 = st[pix + 1];
    const unsigned int* pl = sorted + (size_t)bi * SORT_STRIDE;
    const char* fbB = (const char*)(feat + (((size_t)b) << 19) * NC);
    unsigned int cb = c2 << 3;         // float2 byte offset within 128B row
    __syncthreads();

    const float* Atrow = At9[bi];
    float accx = 0.f, accy = 0.f, wsum = 0.f;
    for (unsigned int k0 = s0; k0 < e0; k0 += 8) {
        uint4 pa = *(const uint4*)(pl + k0);
        uint4 pb = *(const uint4*)(pl + k0 + 4);
        unsigned int pv[8] = {pa.x, pa.y, pa.z, pa.w, pb.x, pb.y, pb.z, pb.w};
        #pragma unroll
        for (int h = 0; h < 8; h++) {
            unsigned int baddr = (pv[h] & 0x03FFFF80u) | cb;
            float2 fv = *(const float2*)(fbB + baddr);  // sentinel -> row 0
            float w = Atrow[pv[h] >> 27];               // sentinel -> 0.0
            accx = fmaf(w, fv.x, accx);
            accy = fmaf(w, fv.y, accy);
            wsum += w;
        }
    }

    // ---- wave-local MFMA epilogue (no LDS, no barrier); 4 rows per wave ----
    // A-frag lane l: tile row r=l&15 (valid r<4 = wave subgroup r), k=(l>>4)*8+j.
    // Source: row r's channel k held by wave-lane (r<<4)|(k>>1), component k&1 (=j&1).
    short8 af;
    int r = l & 15;
    int kb = l >> 4;
    #pragma unroll
    for (int j = 0; j < 8; j++) {
        int k = kb * 8 + j;
        int srcl = (((r & 3) << 4) | (k >> 1)) & 63;
        float v = __shfl((j & 1) ? accy : accx, srcl, 64);
        af[j] = (r < 4) ? (short)f2bf(v) : (short)0;
    }
    float wsr[4];
    #pragma unroll
    for (int q = 0; q < 4; q++) wsr[q] = __shfl(wsum, q << 4, 64);
    float bias0 = blin[l & 15];
    float bias1 = blin[16 + (l & 15)];
    f32x4 c0, c1;
    #pragma unroll
    for (int q = 0; q < 4; q++) {
        float wv = (kb == 0) ? wsr[q] : 0.f;  // rows 0-3 only (kb==0 quadrant)
        c0[q] = bias0 * wv;
        c1[q] = bias1 * wv;
    }
    c0 = __builtin_amdgcn_mfma_f32_16x16x32_bf16(af, bf0, c0, 0, 0, 0);
    c1 = __builtin_amdgcn_mfma_f32_16x16x32_bf16(af, bf1, c1, 0, 0, 0);
    if (l < 16) {
        size_t rowbase = (size_t)blockIdx.x * 16 + (t >> 6) * 4; // wave's 4 rows
        #pragma unroll
        for (int q = 0; q < 4; q++) {
            __builtin_nontemporal_store(c0[q], &out[(rowbase + q) * NC + l]);
            __builtin_nontemporal_store(c1[q], &out[(rowbase + q) * NC + 16 + l]);
        }
    }
}

extern "C" void kernel_launch(void* const* d_in, const int* in_sizes, int n_in,
                              void* d_out, int out_size, void* d_ws, size_t ws_size,
                              hipStream_t stream)
{
    const float* features = (const float*)d_in[0];
    const float* xy       = (const float*)d_in[1];
    const float* ext      = (const float*)d_in[2];
    const float* Wlin     = (const float*)d_in[3];
    const float* blin     = (const float*)d_in[4];
    float* out = (float*)d_out;

    char* ws = (char*)d_ws;
    float*          At     = (float*)(ws + OFF_AT);
    unsigned int*   start  = (unsigned int*)(ws + OFF_START);
    unsigned int*   cnt    = (unsigned int*)(ws + OFF_CNT);
    unsigned short* pixarr = (unsigned short*)(ws + OFF_PIX);
    unsigned int*   sorted = (unsigned int*)(ws + OFF_SORT);

    adj_kernel<<<1, 256, 0, stream>>>(ext, out + STACKED_ELEMS, At);

    k1_pix<<<(NB * NV * NV * NG) / 1024, 256, 0, stream>>>((const float2*)xy, pixarr);
    k2_hist<<<NBI * RSPLIT, 1024, 0, stream>>>(pixarr, cnt);
    k3_scan<<<NBI, 1024, 0, stream>>>(cnt, start);
    k4_fill<<<NBI * RSPLIT, 1024, 0, stream>>>(pixarr, start, sorted);

    const int nrows_blocks = (NB * NV * NG) / 16; // 131072 blocks x 16 rows
    b_gather<<<nrows_blocks, 256, 0, stream>>>(features, pixarr, start, sorted,
                                               Wlin, blin, At, out);
}

// Round 18
// 740.133 us; speedup vs baseline: 1.3485x; 1.1538x over previous
//
#include <hip/hip_runtime.h>
#include <math.h>

#define NB 4
#define NV 8
#define NC 32
#define NG 65536
#define IMGW 256
#define NBI 32               // NB*NV
#define RSPLIT 8             // pixel-range split per (b,i)
#define RBINS (NG / RSPLIT)  // 8192 bins per range
#define START_STRIDE 65544   // 65536 + sentinel + pad
#define SORT_STRIDE (1u << 20) // padded slot capacity per bi
#define SENTINEL (8u << 27)  // widx=8 (w=0); byte-row masks to 0

static constexpr long long STACKED_ELEMS = (long long)NB * NV * NG * NC; // 67108864

typedef __attribute__((ext_vector_type(8))) short short8;
typedef __attribute__((ext_vector_type(4))) float f32x4;

// ---------------- ws layout ----------------
static constexpr size_t OFF_AT    = 0;
static constexpr size_t OFF_START = 4096;
static constexpr size_t OFF_CNT   = OFF_START + (size_t)NBI * START_STRIDE * 4;
static constexpr size_t OFF_PIX   = OFF_CNT + (size_t)NBI * NG * 4;
static constexpr size_t OFF_SORT  = OFF_PIX + (size_t)NBI * NV * NG * 2;

__device__ __forceinline__ unsigned short f2bf(float f)
{
    unsigned int u = __float_as_uint(f);
    return (unsigned short)((u + 0x7FFFu + ((u >> 16) & 1u)) >> 16);
}

// ---------------- adjacency ----------------
__global__ __launch_bounds__(256) void adj_kernel(const float* __restrict__ ext,
                                                  float* __restrict__ A_out,
                                                  float* __restrict__ At_out)
{
    __shared__ float ctr[NB * NV][3];
    __shared__ float Dsh[NB * NV * NV];
    int t = threadIdx.x;
    if (t < NB * NV) {
        const float* E = ext + t * 16;
        #pragma unroll
        for (int i = 0; i < 3; i++) {
            float s = E[0 * 4 + i] * E[0 * 4 + 3]
                    + E[1 * 4 + i] * E[1 * 4 + 3]
                    + E[2 * 4 + i] * E[2 * 4 + 3];
            ctr[t][i] = -s;
        }
    }
    __syncthreads();
    {
        int b = t >> 6, i = (t >> 3) & 7, j = t & 7;
        float dx = ctr[b * 8 + i][0] - ctr[b * 8 + j][0];
        float dy = ctr[b * 8 + i][1] - ctr[b * 8 + j][1];
        float dz = ctr[b * 8 + i][2] - ctr[b * 8 + j][2];
        Dsh[t] = dx * dx + dy * dy + dz * dz;
    }
    __syncthreads();
    if (t < NB * NV) {
        int ri = t & 7;
        const float* drow = &Dsh[t * 8];
        bool chosen[8] = {false, false, false, false, false, false, false, false};
        for (int n = 0; n < 3; n++) {
            int best = -1; float bs = -3.0e38f;
            for (int j2 = 0; j2 < 8; j2++) {
                if (j2 == ri || chosen[j2]) continue;
                float s = -drow[j2];
                if (s > bs) { bs = s; best = j2; }
            }
            chosen[best] = true;
        }
        float row[8]; float deg = 0.f;
        #pragma unroll
        for (int j2 = 0; j2 < 8; j2++) {
            float a = 0.f;
            if (j2 == ri)        a = 1.0f;
            else if (chosen[j2]) a = 1.0f / (1.0f + sqrtf(drow[j2] + 1e-6f));
            row[j2] = a; deg += a;
        }
        float dn = deg + (deg == 0.f ? 1.f : 0.f);
        #pragma unroll
        for (int j2 = 0; j2 < 8; j2++) {
            A_out[t * 8 + j2]  = row[j2];
            At_out[t * 8 + j2] = row[j2] / dn;
        }
    }
}

// ---------------- k1: pixel precompute ----------------
__global__ __launch_bounds__(256) void k1_pix(const float2* __restrict__ xy,
                                              unsigned short* __restrict__ pixarr)
{
    unsigned int base = blockIdx.x * 1024 + threadIdx.x;
    #pragma unroll
    for (int k = 0; k < 4; k++) {
        unsigned int tid = base + k * 256; // [b][j][i][g]
        float2 p = xy[tid];
        float px = fminf(fmaxf(rintf(p.x), 0.f), (float)(IMGW - 1));
        float py = fminf(fmaxf(rintf(p.y), 0.f), (float)(IMGW - 1));
        unsigned int pix = (unsigned int)py * IMGW + (unsigned int)px;
        unsigned int g = tid & 0xFFFFu;
        unsigned int i = (tid >> 16) & 7u;
        unsigned int j = (tid >> 19) & 7u;
        unsigned int b = tid >> 22;
        unsigned int bi = (b << 3) | i;
        pixarr[(((bi << 3) | j) << 16) | g] = (unsigned short)pix; // [bi][j][g]
    }
}

// ---------------- k2: LDS histogram; XCD-swizzled; 4x batched loads ----------------
__global__ __launch_bounds__(1024) void k2_hist(const unsigned short* __restrict__ pixarr,
                                                unsigned int* __restrict__ cnt)
{
    __shared__ unsigned int hist[RBINS]; // 32 KB
    int t = threadIdx.x;
    unsigned int bi = blockIdx.x & 31u;  // XCD = bi%8
    unsigned int r  = blockIdx.x >> 5;
    unsigned int r0 = r * RBINS;
    for (int k = t; k < RBINS; k += 1024) hist[k] = 0;
    __syncthreads();
    const uint4* src = (const uint4*)(pixarr + ((size_t)bi << 19));
    for (int it = 0; it < 16; it++) {
        uint4 vv[4];
        #pragma unroll
        for (int q = 0; q < 4; q++)
            vv[q] = src[t + (it * 4 + q) * 1024]; // 4 independent loads in flight
        #pragma unroll
        for (int q = 0; q < 4; q++) {
            const unsigned int* vw = (const unsigned int*)&vv[q];
            #pragma unroll
            for (int h = 0; h < 4; h++) {
                unsigned int w = vw[h];
                unsigned int p0 = (w & 0xFFFFu) - r0;
                unsigned int p1 = (w >> 16) - r0;
                if (p0 < RBINS) atomicAdd(&hist[p0], 1u);
                if (p1 < RBINS) atomicAdd(&hist[p1], 1u);
            }
        }
    }
    __syncthreads();
    unsigned int* dst = cnt + ((size_t)bi << 16) + r0;
    for (int k = t; k < RBINS; k += 1024) dst[k] = hist[k];
}

// ---------------- k3: exclusive scan of PADDED counts ----------------
__global__ __launch_bounds__(1024) void k3_scan(const unsigned int* __restrict__ cnt,
                                                unsigned int* __restrict__ start)
{
    __shared__ unsigned int lds[1024];
    int bi = blockIdx.x;
    const unsigned int* c = cnt + ((size_t)bi << 16);
    unsigned int* st = start + (size_t)bi * START_STRIDE;
    int t = threadIdx.x;
    unsigned int s = 0;
    for (int k = 0; k < 64; k++) s += (c[t * 64 + k] + 7u) & ~7u;
    lds[t] = s;
    __syncthreads();
    for (int off = 1; off < 1024; off <<= 1) {
        unsigned int v = (t >= off) ? lds[t - off] : 0u;
        __syncthreads();
        lds[t] += v;
        __syncthreads();
    }
    unsigned int run = lds[t] - s;
    for (int k = 0; k < 64; k++) {
        unsigned int cv = (c[t * 64 + k] + 7u) & ~7u;
        st[t * 64 + k] = run;
        run += cv;
    }
    if (t == 1023) st[NG] = run;
}

// ---------------- k4: counting-sort fill + sentinel padding; 4x batched loads ----------------
__global__ __launch_bounds__(1024) void k4_fill(const unsigned short* __restrict__ pixarr,
                                                const unsigned int* __restrict__ start,
                                                unsigned int* __restrict__ sorted)
{
    __shared__ unsigned int cur[RBINS]; // 32 KB
    int t = threadIdx.x;
    unsigned int bi = blockIdx.x & 31u;  // XCD = bi%8
    unsigned int r  = blockIdx.x >> 5;
    unsigned int r0 = r * RBINS;
    const unsigned int* stg = start + (size_t)bi * START_STRIDE;
    for (int k = t; k < RBINS; k += 1024) cur[k] = stg[r0 + k];
    __syncthreads();
    const uint4* src = (const uint4*)(pixarr + ((size_t)bi << 19));
    unsigned int* dstbase = sorted + (size_t)bi * SORT_STRIDE;
    for (int it = 0; it < 16; it++) {
        uint4 vv[4];
        #pragma unroll
        for (int q = 0; q < 4; q++)
            vv[q] = src[t + (it * 4 + q) * 1024];
        #pragma unroll
        for (int q = 0; q < 4; q++) {
            unsigned int m0 = (t + (it * 4 + q) * 1024) * 8;
            const unsigned int* vw = (const unsigned int*)&vv[q];
            #pragma unroll
            for (int h = 0; h < 8; h++) {
                unsigned int w = vw[h >> 1];
                unsigned int pv = ((h & 1) ? (w >> 16) : (w & 0xFFFFu)) - r0;
                if (pv < RBINS) {
                    unsigned int slot = atomicAdd(&cur[pv], 1u);
                    unsigned int m = m0 + h;                      // (j<<16)|g
                    dstbase[slot] = ((m >> 16) << 27) | (m << 7); // (j<<27)|(rowidx<<7)
                }
            }
        }
    }
    __syncthreads();
    for (int k = t; k < RBINS; k += 1024) {
        unsigned int e = stg[r0 + k + 1];
        for (unsigned int x = cur[k]; x < e; x++) dstbase[x] = SENTINEL;
    }
}

// ---------------- b_gather: 4-channel lanes (8/row) + wave-local MFMA epilogue ----------------
// 256 threads = 32 groups of 8; group = one output row; lane owns channels 4c..4c+3 (float4).
// Wave = 8 rows. Epilogue: A-frag rows 0-7 via shfl (components from 2 src lanes);
// 2x mfma_f32_16x16x32_bf16; C init = bias*wsum on kb<2 quadrants; store via lanes<32.
__global__ __launch_bounds__(256) void b_gather(
    const float* __restrict__ feat,
    const unsigned short* __restrict__ pixarr,
    const unsigned int* __restrict__ start,
    const unsigned int* __restrict__ sorted,
    const float* __restrict__ Wlin,
    const float* __restrict__ blin,
    const float* __restrict__ At,
    float* __restrict__ out)
{
    __shared__ float At9[NBI][16];     // 9-wide weight rows (index 8 = 0.0)
    int t = threadIdx.x;
    int c4 = t & 7;                    // channel quad index
    int grp = t >> 3;                  // 0..31 = row within block

    unsigned int rrow = blockIdx.x * 32 + grp; // [bi][g]
    unsigned int g = rrow & 0xFFFFu;
    unsigned int bi = rrow >> 16;      // uniform per block (2048 blocks per bi)
    unsigned int i = bi & 7u;
    unsigned int b = bi >> 3;
    unsigned int pix = pixarr[(((bi << 3) | i) << 16) | g];

    At9[t >> 3][t & 7] = At[t];
    At9[t >> 3][8 + (t & 7)] = 0.f;

    // preload W fragments (L2-hot, uniform)
    int l = t & 63;
    short8 bf0, bf1;
    #pragma unroll
    for (int j = 0; j < 8; j++) {
        int kk = (l >> 4) * 8 + j;
        bf0[j] = (short)f2bf(Wlin[kk * NC + (l & 15)]);
        bf1[j] = (short)f2bf(Wlin[kk * NC + 16 + (l & 15)]);
    }

    const unsigned int* st = start + (size_t)bi * START_STRIDE;
    unsigned int s0 = st[pix];
    unsigned int e0 = st[pix + 1];
    const unsigned int* pl = sorted + (size_t)bi * SORT_STRIDE;
    const char* fbB = (const char*)(feat + (((size_t)b) << 19) * NC);
    unsigned int cb = c4 << 4;         // float4 byte offset within 128B row
    __syncthreads();

    const float* Atrow = At9[bi];
    float ax = 0.f, ay = 0.f, az = 0.f, aw = 0.f, wsum = 0.f;
    for (unsigned int k0 = s0; k0 < e0; k0 += 8) {
        uint4 pa = *(const uint4*)(pl + k0);
        uint4 pb = *(const uint4*)(pl + k0 + 4);
        unsigned int pv[8] = {pa.x, pa.y, pa.z, pa.w, pb.x, pb.y, pb.z, pb.w};
        #pragma unroll
        for (int h = 0; h < 8; h++) {
            unsigned int baddr = (pv[h] & 0x03FFFF80u) | cb;
            float4 fv = *(const float4*)(fbB + baddr);  // sentinel -> row 0
            float w = Atrow[pv[h] >> 27];               // sentinel -> 0.0
            ax = fmaf(w, fv.x, ax);
            ay = fmaf(w, fv.y, ay);
            az = fmaf(w, fv.z, az);
            aw = fmaf(w, fv.w, aw);
            wsum += w;
        }
    }

    // ---- wave-local MFMA epilogue (no LDS, no barrier); 8 rows per wave ----
    // A-frag lane l: tile row r=l&15 (valid r<8), k=kb*8+j (kb=l>>4).
    // Row r channel k held by wave-lane (r<<3)|(k>>2), component k&3.
    int r = l & 15;
    int kb = l >> 4;
    int s0l = (((r & 7) << 3) | (kb << 1)) & 63;  // j=0..3 source lane
    int s1l = s0l | 1;                            // j=4..7 source lane
    float v0x = __shfl(ax, s0l, 64), v0y = __shfl(ay, s0l, 64);
    float v0z = __shfl(az, s0l, 64), v0w = __shfl(aw, s0l, 64);
    float v1x = __shfl(ax, s1l, 64), v1y = __shfl(ay, s1l, 64);
    float v1z = __shfl(az, s1l, 64), v1w = __shfl(aw, s1l, 64);
    short8 af;
    if (r < 8) {
        af[0] = (short)f2bf(v0x); af[1] = (short)f2bf(v0y);
        af[2] = (short)f2bf(v0z); af[3] = (short)f2bf(v0w);
        af[4] = (short)f2bf(v1x); af[5] = (short)f2bf(v1y);
        af[6] = (short)f2bf(v1z); af[7] = (short)f2bf(v1w);
    } else {
        af = short8{0, 0, 0, 0, 0, 0, 0, 0};
    }
    float bias0 = blin[l & 15];
    float bias1 = blin[16 + (l & 15)];
    f32x4 c0, c1;
    #pragma unroll
    for (int q = 0; q < 4; q++) {
        int row = kb * 4 + q;                       // C/D row for reg q
        float wv = __shfl(wsum, (row << 3) & 63, 64);
        wv = (row < 8) ? wv : 0.f;
        c0[q] = bias0 * wv;
        c1[q] = bias1 * wv;
    }
    c0 = __builtin_amdgcn_mfma_f32_16x16x32_bf16(af, bf0, c0, 0, 0, 0);
    c1 = __builtin_amdgcn_mfma_f32_16x16x32_bf16(af, bf1, c1, 0, 0, 0);
    if (l < 32) {
        size_t rowbase = (size_t)blockIdx.x * 32 + (t >> 6) * 8; // wave's 8 rows
        #pragma unroll
        for (int q = 0; q < 4; q++) {
            size_t rr = rowbase + (l >> 4) * 4 + q;  // rows 0-7 across lanes 0-31
            __builtin_nontemporal_store(c0[q], &out[rr * NC + (l & 15)]);
            __builtin_nontemporal_store(c1[q], &out[rr * NC + 16 + (l & 15)]);
        }
    }
}

extern "C" void kernel_launch(void* const* d_in, const int* in_sizes, int n_in,
                              void* d_out, int out_size, void* d_ws, size_t ws_size,
                              hipStream_t stream)
{
    const float* features = (const float*)d_in[0];
    const float* xy       = (const float*)d_in[1];
    const float* ext      = (const float*)d_in[2];
    const float* Wlin     = (const float*)d_in[3];
    const float* blin     = (const float*)d_in[4];
    float* out = (float*)d_out;

    char* ws = (char*)d_ws;
    float*          At     = (float*)(ws + OFF_AT);
    unsigned int*   start  = (unsigned int*)(ws + OFF_START);
    unsigned int*   cnt    = (unsigned int*)(ws + OFF_CNT);
    unsigned short* pixarr = (unsigned short*)(ws + OFF_PIX);
    unsigned int*   sorted = (unsigned int*)(ws + OFF_SORT);

    adj_kernel<<<1, 256, 0, stream>>>(ext, out + STACKED_ELEMS, At);

    k1_pix<<<(NB * NV * NV * NG) / 1024, 256, 0, stream>>>((const float2*)xy, pixarr);
    k2_hist<<<NBI * RSPLIT, 1024, 0, stream>>>(pixarr, cnt);
    k3_scan<<<NBI, 1024, 0, stream>>>(cnt, start);
    k4_fill<<<NBI * RSPLIT, 1024, 0, stream>>>(pixarr, start, sorted);

    const int nrows_blocks = (NB * NV * NG) / 32; // 65536 blocks x 32 rows
    b_gather<<<nrows_blocks, 256, 0, stream>>>(features, pixarr, start, sorted,
                                               Wlin, blin, At, out);
}

// Round 20
// 730.770 us; speedup vs baseline: 1.3658x; 1.0128x over previous
//
#include <hip/hip_runtime.h>
#include <math.h>

#define NB 4
#define NV 8
#define NC 32
#define NG 65536
#define IMGW 256
#define NBI 32               // NB*NV
#define RSPLIT 8             // pixel-range split per (b,i)
#define RBINS (NG / RSPLIT)  // 8192 bins per range
#define START_STRIDE 65544   // 65536 + sentinel + pad
#define SORT_STRIDE (1u << 20) // padded slot capacity per bi
#define SENTINEL (8u << 27)  // widx=8 (w=0); byte-row masks to 0

static constexpr long long STACKED_ELEMS = (long long)NB * NV * NG * NC; // 67108864

typedef __attribute__((ext_vector_type(8))) short short8;
typedef __attribute__((ext_vector_type(4))) float f32x4;
typedef __attribute__((ext_vector_type(4))) unsigned int u32x4;

// ---------------- ws layout ----------------
static constexpr size_t OFF_AT    = 0;      // 1 KB
static constexpr size_t OFF_RTOT  = 1024;   // 256 u32
static constexpr size_t OFF_RBASE = 2048;   // 32*9 u32
static constexpr size_t OFF_START = 4096;
static constexpr size_t OFF_CNT   = OFF_START + (size_t)NBI * START_STRIDE * 4;
static constexpr size_t OFF_PIX   = OFF_CNT + (size_t)NBI * NG * 4;
static constexpr size_t OFF_SORT  = OFF_PIX + (size_t)NBI * NV * NG * 2;

__device__ __forceinline__ unsigned short f2bf(float f)
{
    unsigned int u = __float_as_uint(f);
    return (unsigned short)((u + 0x7FFFu + ((u >> 16) & 1u)) >> 16);
}

// ---------------- adjacency ----------------
__global__ __launch_bounds__(256) void adj_kernel(const float* __restrict__ ext,
                                                  float* __restrict__ A_out,
                                                  float* __restrict__ At_out)
{
    __shared__ float ctr[NB * NV][3];
    __shared__ float Dsh[NB * NV * NV];
    int t = threadIdx.x;
    if (t < NB * NV) {
        const float* E = ext + t * 16;
        #pragma unroll
        for (int i = 0; i < 3; i++) {
            float s = E[0 * 4 + i] * E[0 * 4 + 3]
                    + E[1 * 4 + i] * E[1 * 4 + 3]
                    + E[2 * 4 + i] * E[2 * 4 + 3];
            ctr[t][i] = -s;
        }
    }
    __syncthreads();
    {
        int b = t >> 6, i = (t >> 3) & 7, j = t & 7;
        float dx = ctr[b * 8 + i][0] - ctr[b * 8 + j][0];
        float dy = ctr[b * 8 + i][1] - ctr[b * 8 + j][1];
        float dz = ctr[b * 8 + i][2] - ctr[b * 8 + j][2];
        Dsh[t] = dx * dx + dy * dy + dz * dz;
    }
    __syncthreads();
    if (t < NB * NV) {
        int ri = t & 7;
        const float* drow = &Dsh[t * 8];
        bool chosen[8] = {false, false, false, false, false, false, false, false};
        for (int n = 0; n < 3; n++) {
            int best = -1; float bs = -3.0e38f;
            for (int j2 = 0; j2 < 8; j2++) {
                if (j2 == ri || chosen[j2]) continue;
                float s = -drow[j2];
                if (s > bs) { bs = s; best = j2; }
            }
            chosen[best] = true;
        }
        float row[8]; float deg = 0.f;
        #pragma unroll
        for (int j2 = 0; j2 < 8; j2++) {
            float a = 0.f;
            if (j2 == ri)        a = 1.0f;
            else if (chosen[j2]) a = 1.0f / (1.0f + sqrtf(drow[j2] + 1e-6f));
            row[j2] = a; deg += a;
        }
        float dn = deg + (deg == 0.f ? 1.f : 0.f);
        #pragma unroll
        for (int j2 = 0; j2 < 8; j2++) {
            A_out[t * 8 + j2]  = row[j2];
            At_out[t * 8 + j2] = row[j2] / dn;
        }
    }
}

// ---------------- k1: pixel precompute ----------------
__global__ __launch_bounds__(256) void k1_pix(const float2* __restrict__ xy,
                                              unsigned short* __restrict__ pixarr)
{
    unsigned int base = blockIdx.x * 1024 + threadIdx.x;
    #pragma unroll
    for (int k = 0; k < 4; k++) {
        unsigned int tid = base + k * 256; // [b][j][i][g]
        float2 p = xy[tid];
        float px = fminf(fmaxf(rintf(p.x), 0.f), (float)(IMGW - 1));
        float py = fminf(fmaxf(rintf(p.y), 0.f), (float)(IMGW - 1));
        unsigned int pix = (unsigned int)py * IMGW + (unsigned int)px;
        unsigned int g = tid & 0xFFFFu;
        unsigned int i = (tid >> 16) & 7u;
        unsigned int j = (tid >> 19) & 7u;
        unsigned int b = tid >> 22;
        unsigned int bi = (b << 3) | i;
        pixarr[(((bi << 3) | j) << 16) | g] = (unsigned short)pix; // [bi][j][g]
    }
}

// ---------------- k2: LDS histogram + padded range totals; XCD-swizzled ----------------
__global__ __launch_bounds__(1024) void k2_hist(const unsigned short* __restrict__ pixarr,
                                                unsigned int* __restrict__ cnt,
                                                unsigned int* __restrict__ rtot)
{
    __shared__ unsigned int hist[RBINS]; // 32 KB
    int t = threadIdx.x;
    unsigned int bi = blockIdx.x & 31u;  // XCD = bi%8
    unsigned int r  = blockIdx.x >> 5;
    unsigned int r0 = r * RBINS;
    for (int k = t; k < RBINS; k += 1024) hist[k] = 0;
    __syncthreads();
    const uint4* src = (const uint4*)(pixarr + ((size_t)bi << 19));
    for (int it = 0; it < 16; it++) {
        uint4 vv[4];
        #pragma unroll
        for (int q = 0; q < 4; q++)
            vv[q] = src[t + (it * 4 + q) * 1024];
        #pragma unroll
        for (int q = 0; q < 4; q++) {
            const unsigned int* vw = (const unsigned int*)&vv[q];
            #pragma unroll
            for (int h = 0; h < 4; h++) {
                unsigned int w = vw[h];
                unsigned int p0 = (w & 0xFFFFu) - r0;
                unsigned int p1 = (w >> 16) - r0;
                if (p0 < RBINS) atomicAdd(&hist[p0], 1u);
                if (p1 < RBINS) atomicAdd(&hist[p1], 1u);
            }
        }
    }
    __syncthreads();
    unsigned int* dst = cnt + ((size_t)bi << 16) + r0;
    unsigned int psum = 0;
    for (int k = t; k < RBINS; k += 1024) {
        unsigned int v = hist[k];
        dst[k] = v;
        psum += (v + 7u) & ~7u;
    }
    __syncthreads();
    hist[t] = psum;
    __syncthreads();
    for (int off = 512; off; off >>= 1) {
        if (t < off) hist[t] += hist[t + off];
        __syncthreads();
    }
    if (t == 0) rtot[bi * 8 + r] = hist[0];
}

// ---------------- k3b: per-bi scan of 8 padded range totals ----------------
__global__ __launch_bounds__(64) void k3b_rscan(const unsigned int* __restrict__ rtot,
                                                unsigned int* __restrict__ rbase)
{
    int t = threadIdx.x;
    if (t < 32) {
        unsigned int run = 0;
        #pragma unroll
        for (int q = 0; q < 8; q++) {
            rbase[t * 9 + q] = run;
            run += rtot[t * 8 + q];
        }
        rbase[t * 9 + 8] = run;
    }
}

// ---------------- k3c: coalesced per-(bi,r) bin scan via LDS ----------------
__global__ __launch_bounds__(1024) void k3c_scan(const unsigned int* __restrict__ cnt,
                                                 const unsigned int* __restrict__ rbase,
                                                 unsigned int* __restrict__ start)
{
    __shared__ unsigned int lc[RBINS]; // 32 KB
    __shared__ unsigned int bs[1024];
    int t = threadIdx.x;
    unsigned int bi = blockIdx.x & 31u;
    unsigned int r  = blockIdx.x >> 5;
    unsigned int r0 = r * RBINS;
    const unsigned int* c = cnt + ((size_t)bi << 16) + r0;
    #pragma unroll
    for (int q = 0; q < 8; q++)
        lc[q * 1024 + t] = (c[q * 1024 + t] + 7u) & ~7u; // coalesced, padded
    __syncthreads();
    unsigned int v[8]; unsigned int s = 0;
    #pragma unroll
    for (int k = 0; k < 8; k++) { v[k] = s; s += lc[t * 8 + k]; } // contiguous run
    bs[t] = s;
    __syncthreads();
    for (int off = 1; off < 1024; off <<= 1) {
        unsigned int u = (t >= off) ? bs[t - off] : 0u;
        __syncthreads();
        bs[t] += u;
        __syncthreads();
    }
    unsigned int base = rbase[bi * 9 + r] + bs[t] - s; // exclusive prefix
    #pragma unroll
    for (int k = 0; k < 8; k++) lc[t * 8 + k] = base + v[k];
    __syncthreads();
    unsigned int* st_ = start + (size_t)bi * START_STRIDE + r0;
    #pragma unroll
    for (int q = 0; q < 8; q++)
        st_[q * 1024 + t] = lc[q * 1024 + t]; // coalesced
    if (r == 7 && t == 0)
        start[(size_t)bi * START_STRIDE + NG] = rbase[bi * 9 + 8];
}

// ---------------- k4: counting-sort fill + sentinel padding; 4x batched loads ----------------
__global__ __launch_bounds__(1024) void k4_fill(const unsigned short* __restrict__ pixarr,
                                                const unsigned int* __restrict__ start,
                                                unsigned int* __restrict__ sorted)
{
    __shared__ unsigned int cur[RBINS]; // 32 KB
    int t = threadIdx.x;
    unsigned int bi = blockIdx.x & 31u;  // XCD = bi%8
    unsigned int r  = blockIdx.x >> 5;
    unsigned int r0 = r * RBINS;
    const unsigned int* stg = start + (size_t)bi * START_STRIDE;
    for (int k = t; k < RBINS; k += 1024) cur[k] = stg[r0 + k];
    __syncthreads();
    const uint4* src = (const uint4*)(pixarr + ((size_t)bi << 19));
    unsigned int* dstbase = sorted + (size_t)bi * SORT_STRIDE;
    for (int it = 0; it < 16; it++) {
        uint4 vv[4];
        #pragma unroll
        for (int q = 0; q < 4; q++)
            vv[q] = src[t + (it * 4 + q) * 1024];
        #pragma unroll
        for (int q = 0; q < 4; q++) {
            unsigned int m0 = (t + (it * 4 + q) * 1024) * 8;
            const unsigned int* vw = (const unsigned int*)&vv[q];
            #pragma unroll
            for (int h = 0; h < 8; h++) {
                unsigned int w = vw[h >> 1];
                unsigned int pv = ((h & 1) ? (w >> 16) : (w & 0xFFFFu)) - r0;
                if (pv < RBINS) {
                    unsigned int slot = atomicAdd(&cur[pv], 1u);
                    unsigned int m = m0 + h;                      // (j<<16)|g
                    dstbase[slot] = ((m >> 16) << 27) | (m << 7); // (j<<27)|(rowidx<<7)
                }
            }
        }
    }
    __syncthreads();
    for (int k = t; k < RBINS; k += 1024) {
        unsigned int e = stg[r0 + k + 1];
        for (unsigned int x = cur[k]; x < e; x++) dstbase[x] = SENTINEL;
    }
}

// ---------------- b_gather: i-interleaved blocks, 8 lanes/row, MFMA epilogue ----------------
// blockIdx -> (b, gc, i) with i = blockIdx&7: consecutive blocks share feat[b]
// (L3-resident slab) and each XCD owns one i (sorted[bi] L2-resident).
__global__ __launch_bounds__(256) void b_gather(
    const float* __restrict__ feat,
    const unsigned short* __restrict__ pixarr,
    const unsigned int* __restrict__ start,
    const unsigned int* __restrict__ sorted,
    const float* __restrict__ Wlin,
    const float* __restrict__ blin,
    const float* __restrict__ At,
    float* __restrict__ out)
{
    __shared__ float At9[NBI][16];     // 9-wide weight rows (index 8 = 0.0)
    int t = threadIdx.x;
    int c4 = t & 7;                    // channel quad index
    int grp = t >> 3;                  // 0..31 = row within block

    unsigned int bidx = blockIdx.x;
    unsigned int b  = bidx >> 14;          // 16384 blocks per b
    unsigned int i  = bidx & 7u;           // XCD-pinned view
    unsigned int gc = (bidx >> 3) & 2047u; // g-chunk
    unsigned int bi = (b << 3) | i;
    unsigned int g0 = gc << 5;             // 32 rows per block
    unsigned int g = g0 + grp;
    unsigned int pix = pixarr[(((bi << 3) | i) << 16) | g];

    At9[t >> 3][t & 7] = At[t];
    At9[t >> 3][8 + (t & 7)] = 0.f;

    // preload W fragments (L2-hot, uniform)
    int l = t & 63;
    short8 bf0, bf1;
    #pragma unroll
    for (int j = 0; j < 8; j++) {
        int kk = (l >> 4) * 8 + j;
        bf0[j] = (short)f2bf(Wlin[kk * NC + (l & 15)]);
        bf1[j] = (short)f2bf(Wlin[kk * NC + 16 + (l & 15)]);
    }

    const unsigned int* st = start + (size_t)bi * START_STRIDE;
    unsigned int s0 = st[pix];
    unsigned int e0 = st[pix + 1];
    const unsigned int* pl = sorted + (size_t)bi * SORT_STRIDE;
    const char* fbB = (const char*)(feat + (((size_t)b) << 19) * NC);
    unsigned int cb = c4 << 4;         // float4 byte offset within 128B row
    __syncthreads();

    const float* Atrow = At9[bi];
    float ax = 0.f, ay = 0.f, az = 0.f, aw = 0.f, wsum = 0.f;
    for (unsigned int k0 = s0; k0 < e0; k0 += 8) {
        u32x4 pa = __builtin_nontemporal_load((const u32x4*)(pl + k0));
        u32x4 pb = __builtin_nontemporal_load((const u32x4*)(pl + k0 + 4));
        unsigned int pv[8] = {pa.x, pa.y, pa.z, pa.w, pb.x, pb.y, pb.z, pb.w};
        #pragma unroll
        for (int h = 0; h < 8; h++) {
            unsigned int baddr = (pv[h] & 0x03FFFF80u) | cb;
            float4 fv = *(const float4*)(fbB + baddr);  // sentinel -> row 0
            float w = Atrow[pv[h] >> 27];               // sentinel -> 0.0
            ax = fmaf(w, fv.x, ax);
            ay = fmaf(w, fv.y, ay);
            az = fmaf(w, fv.z, az);
            aw = fmaf(w, fv.w, aw);
            wsum += w;
        }
    }

    // ---- wave-local MFMA epilogue (no LDS, no barrier); 8 rows per wave ----
    int r = l & 15;
    int kb = l >> 4;
    int s0l = (((r & 7) << 3) | (kb << 1)) & 63;  // j=0..3 source lane
    int s1l = s0l | 1;                            // j=4..7 source lane
    float v0x = __shfl(ax, s0l, 64), v0y = __shfl(ay, s0l, 64);
    float v0z = __shfl(az, s0l, 64), v0w = __shfl(aw, s0l, 64);
    float v1x = __shfl(ax, s1l, 64), v1y = __shfl(ay, s1l, 64);
    float v1z = __shfl(az, s1l, 64), v1w = __shfl(aw, s1l, 64);
    short8 af;
    if (r < 8) {
        af[0] = (short)f2bf(v0x); af[1] = (short)f2bf(v0y);
        af[2] = (short)f2bf(v0z); af[3] = (short)f2bf(v0w);
        af[4] = (short)f2bf(v1x); af[5] = (short)f2bf(v1y);
        af[6] = (short)f2bf(v1z); af[7] = (short)f2bf(v1w);
    } else {
        af = short8{0, 0, 0, 0, 0, 0, 0, 0};
    }
    float bias0 = blin[l & 15];
    float bias1 = blin[16 + (l & 15)];
    f32x4 c0, c1;
    #pragma unroll
    for (int q = 0; q < 4; q++) {
        int row = kb * 4 + q;                       // C/D row for reg q
        float wv = __shfl(wsum, (row << 3) & 63, 64);
        wv = (row < 8) ? wv : 0.f;
        c0[q] = bias0 * wv;
        c1[q] = bias1 * wv;
    }
    c0 = __builtin_amdgcn_mfma_f32_16x16x32_bf16(af, bf0, c0, 0, 0, 0);
    c1 = __builtin_amdgcn_mfma_f32_16x16x32_bf16(af, bf1, c1, 0, 0, 0);
    if (l < 32) {
        size_t rowbase = (((size_t)bi << 16) | g0) + (t >> 6) * 8; // wave's 8 rows
        #pragma unroll
        for (int q = 0; q < 4; q++) {
            size_t rr = rowbase + (l >> 4) * 4 + q;  // rows 0-7 across lanes 0-31
            __builtin_nontemporal_store(c0[q], &out[rr * NC + (l & 15)]);
            __builtin_nontemporal_store(c1[q], &out[rr * NC + 16 + (l & 15)]);
        }
    }
}

extern "C" void kernel_launch(void* const* d_in, const int* in_sizes, int n_in,
                              void* d_out, int out_size, void* d_ws, size_t ws_size,
                              hipStream_t stream)
{
    const float* features = (const float*)d_in[0];
    const float* xy       = (const float*)d_in[1];
    const float* ext      = (const float*)d_in[2];
    const float* Wlin     = (const float*)d_in[3];
    const float* blin     = (const float*)d_in[4];
    float* out = (float*)d_out;

    char* ws = (char*)d_ws;
    float*          At     = (float*)(ws + OFF_AT);
    unsigned int*   rtot   = (unsigned int*)(ws + OFF_RTOT);
    unsigned int*   rbase  = (unsigned int*)(ws + OFF_RBASE);
    unsigned int*   start  = (unsigned int*)(ws + OFF_START);
    unsigned int*   cnt    = (unsigned int*)(ws + OFF_CNT);
    unsigned short* pixarr = (unsigned short*)(ws + OFF_PIX);
    unsigned int*   sorted = (unsigned int*)(ws + OFF_SORT);

    adj_kernel<<<1, 256, 0, stream>>>(ext, out + STACKED_ELEMS, At);

    k1_pix<<<(NB * NV * NV * NG) / 1024, 256, 0, stream>>>((const float2*)xy, pixarr);
    k2_hist<<<NBI * RSPLIT, 1024, 0, stream>>>(pixarr, cnt, rtot);
    k3b_rscan<<<1, 64, 0, stream>>>(rtot, rbase);
    k3c_scan<<<NBI * RSPLIT, 1024, 0, stream>>>(cnt, rbase, start);
    k4_fill<<<NBI * RSPLIT, 1024, 0, stream>>>(pixarr, start, sorted);

    const int nrows_blocks = (NB * NV * NG) / 32; // 65536 blocks x 32 rows
    b_gather<<<nrows_blocks, 256, 0, stream>>>(features, pixarr, start, sorted,
                                               Wlin, blin, At, out);
}

// Round 21
// 729.672 us; speedup vs baseline: 1.3678x; 1.0015x over previous
//
#include <hip/hip_runtime.h>
#include <math.h>

#define NB 4
#define NV 8
#define NC 32
#define NG 65536
#define IMGW 256
#define NBI 32               // NB*NV
#define RSPLIT 8             // pixel-range split per (b,i)
#define RBINS (NG / RSPLIT)  // 8192 bins per range
#define START_STRIDE 65544   // 65536 + sentinel + pad
#define SORT_STRIDE (1u << 20) // padded slot capacity per bi
#define SENTINEL (8u << 27)  // widx=8 (w=0); byte-row masks to 0

static constexpr long long STACKED_ELEMS = (long long)NB * NV * NG * NC; // 67108864

typedef __attribute__((ext_vector_type(8))) short short8;
typedef __attribute__((ext_vector_type(4))) float f32x4;
typedef __attribute__((ext_vector_type(4))) unsigned int u32x4;

// ---------------- ws layout ----------------
static constexpr size_t OFF_AT    = 0;      // 1 KB
static constexpr size_t OFF_RTOT  = 1024;   // 256 u32
static constexpr size_t OFF_RBASE = 2048;   // 32*9 u32
static constexpr size_t OFF_START = 4096;
static constexpr size_t OFF_CNT   = OFF_START + (size_t)NBI * START_STRIDE * 4;
static constexpr size_t OFF_PIX   = OFF_CNT + (size_t)NBI * NG * 4;
static constexpr size_t OFF_SORT  = OFF_PIX + (size_t)NBI * NV * NG * 2;

__device__ __forceinline__ unsigned short f2bf(float f)
{
    unsigned int u = __float_as_uint(f);
    return (unsigned short)((u + 0x7FFFu + ((u >> 16) & 1u)) >> 16);
}

// ---------------- adjacency ----------------
__global__ __launch_bounds__(256) void adj_kernel(const float* __restrict__ ext,
                                                  float* __restrict__ A_out,
                                                  float* __restrict__ At_out)
{
    __shared__ float ctr[NB * NV][3];
    __shared__ float Dsh[NB * NV * NV];
    int t = threadIdx.x;
    if (t < NB * NV) {
        const float* E = ext + t * 16;
        #pragma unroll
        for (int i = 0; i < 3; i++) {
            float s = E[0 * 4 + i] * E[0 * 4 + 3]
                    + E[1 * 4 + i] * E[1 * 4 + 3]
                    + E[2 * 4 + i] * E[2 * 4 + 3];
            ctr[t][i] = -s;
        }
    }
    __syncthreads();
    {
        int b = t >> 6, i = (t >> 3) & 7, j = t & 7;
        float dx = ctr[b * 8 + i][0] - ctr[b * 8 + j][0];
        float dy = ctr[b * 8 + i][1] - ctr[b * 8 + j][1];
        float dz = ctr[b * 8 + i][2] - ctr[b * 8 + j][2];
        Dsh[t] = dx * dx + dy * dy + dz * dz;
    }
    __syncthreads();
    if (t < NB * NV) {
        int ri = t & 7;
        const float* drow = &Dsh[t * 8];
        bool chosen[8] = {false, false, false, false, false, false, false, false};
        for (int n = 0; n < 3; n++) {
            int best = -1; float bs = -3.0e38f;
            for (int j2 = 0; j2 < 8; j2++) {
                if (j2 == ri || chosen[j2]) continue;
                float s = -drow[j2];
                if (s > bs) { bs = s; best = j2; }
            }
            chosen[best] = true;
        }
        float row[8]; float deg = 0.f;
        #pragma unroll
        for (int j2 = 0; j2 < 8; j2++) {
            float a = 0.f;
            if (j2 == ri)        a = 1.0f;
            else if (chosen[j2]) a = 1.0f / (1.0f + sqrtf(drow[j2] + 1e-6f));
            row[j2] = a; deg += a;
        }
        float dn = deg + (deg == 0.f ? 1.f : 0.f);
        #pragma unroll
        for (int j2 = 0; j2 < 8; j2++) {
            A_out[t * 8 + j2]  = row[j2];
            At_out[t * 8 + j2] = row[j2] / dn;
        }
    }
}

// ---------------- k1: pixel precompute ----------------
__global__ __launch_bounds__(256) void k1_pix(const float2* __restrict__ xy,
                                              unsigned short* __restrict__ pixarr)
{
    unsigned int base = blockIdx.x * 1024 + threadIdx.x;
    #pragma unroll
    for (int k = 0; k < 4; k++) {
        unsigned int tid = base + k * 256; // [b][j][i][g]
        float2 p = xy[tid];
        float px = fminf(fmaxf(rintf(p.x), 0.f), (float)(IMGW - 1));
        float py = fminf(fmaxf(rintf(p.y), 0.f), (float)(IMGW - 1));
        unsigned int pix = (unsigned int)py * IMGW + (unsigned int)px;
        unsigned int g = tid & 0xFFFFu;
        unsigned int i = (tid >> 16) & 7u;
        unsigned int j = (tid >> 19) & 7u;
        unsigned int b = tid >> 22;
        unsigned int bi = (b << 3) | i;
        pixarr[(((bi << 3) | j) << 16) | g] = (unsigned short)pix; // [bi][j][g]
    }
}

// ---------------- k2: LDS histogram + padded range totals; XCD-swizzled ----------------
__global__ __launch_bounds__(1024) void k2_hist(const unsigned short* __restrict__ pixarr,
                                                unsigned int* __restrict__ cnt,
                                                unsigned int* __restrict__ rtot)
{
    __shared__ unsigned int hist[RBINS]; // 32 KB
    int t = threadIdx.x;
    unsigned int bi = blockIdx.x & 31u;  // XCD = bi%8
    unsigned int r  = blockIdx.x >> 5;
    unsigned int r0 = r * RBINS;
    for (int k = t; k < RBINS; k += 1024) hist[k] = 0;
    __syncthreads();
    const uint4* src = (const uint4*)(pixarr + ((size_t)bi << 19));
    for (int it = 0; it < 16; it++) {
        uint4 vv[4];
        #pragma unroll
        for (int q = 0; q < 4; q++)
            vv[q] = src[t + (it * 4 + q) * 1024];
        #pragma unroll
        for (int q = 0; q < 4; q++) {
            const unsigned int* vw = (const unsigned int*)&vv[q];
            #pragma unroll
            for (int h = 0; h < 4; h++) {
                unsigned int w = vw[h];
                unsigned int p0 = (w & 0xFFFFu) - r0;
                unsigned int p1 = (w >> 16) - r0;
                if (p0 < RBINS) atomicAdd(&hist[p0], 1u);
                if (p1 < RBINS) atomicAdd(&hist[p1], 1u);
            }
        }
    }
    __syncthreads();
    unsigned int* dst = cnt + ((size_t)bi << 16) + r0;
    unsigned int psum = 0;
    for (int k = t; k < RBINS; k += 1024) {
        unsigned int v = hist[k];
        dst[k] = v;
        psum += (v + 7u) & ~7u;
    }
    __syncthreads();
    hist[t] = psum;
    __syncthreads();
    for (int off = 512; off; off >>= 1) {
        if (t < off) hist[t] += hist[t + off];
        __syncthreads();
    }
    if (t == 0) rtot[bi * 8 + r] = hist[0];
}

// ---------------- k3b: per-bi scan of 8 padded range totals ----------------
__global__ __launch_bounds__(64) void k3b_rscan(const unsigned int* __restrict__ rtot,
                                                unsigned int* __restrict__ rbase)
{
    int t = threadIdx.x;
    if (t < 32) {
        unsigned int run = 0;
        #pragma unroll
        for (int q = 0; q < 8; q++) {
            rbase[t * 9 + q] = run;
            run += rtot[t * 8 + q];
        }
        rbase[t * 9 + 8] = run;
    }
}

// ---------------- k3c: coalesced per-(bi,r) bin scan via LDS ----------------
__global__ __launch_bounds__(1024) void k3c_scan(const unsigned int* __restrict__ cnt,
                                                 const unsigned int* __restrict__ rbase,
                                                 unsigned int* __restrict__ start)
{
    __shared__ unsigned int lc[RBINS]; // 32 KB
    __shared__ unsigned int bs[1024];
    int t = threadIdx.x;
    unsigned int bi = blockIdx.x & 31u;
    unsigned int r  = blockIdx.x >> 5;
    unsigned int r0 = r * RBINS;
    const unsigned int* c = cnt + ((size_t)bi << 16) + r0;
    #pragma unroll
    for (int q = 0; q < 8; q++)
        lc[q * 1024 + t] = (c[q * 1024 + t] + 7u) & ~7u; // coalesced, padded
    __syncthreads();
    unsigned int v[8]; unsigned int s = 0;
    #pragma unroll
    for (int k = 0; k < 8; k++) { v[k] = s; s += lc[t * 8 + k]; } // contiguous run
    bs[t] = s;
    __syncthreads();
    for (int off = 1; off < 1024; off <<= 1) {
        unsigned int u = (t >= off) ? bs[t - off] : 0u;
        __syncthreads();
        bs[t] += u;
        __syncthreads();
    }
    unsigned int base = rbase[bi * 9 + r] + bs[t] - s; // exclusive prefix
    #pragma unroll
    for (int k = 0; k < 8; k++) lc[t * 8 + k] = base + v[k];
    __syncthreads();
    unsigned int* st_ = start + (size_t)bi * START_STRIDE + r0;
    #pragma unroll
    for (int q = 0; q < 8; q++)
        st_[q * 1024 + t] = lc[q * 1024 + t]; // coalesced
    if (r == 7 && t == 0)
        start[(size_t)bi * START_STRIDE + NG] = rbase[bi * 9 + 8];
}

// ---------------- k4: counting-sort fill + sentinel padding; 4x batched loads ----------------
__global__ __launch_bounds__(1024) void k4_fill(const unsigned short* __restrict__ pixarr,
                                                const unsigned int* __restrict__ start,
                                                unsigned int* __restrict__ sorted)
{
    __shared__ unsigned int cur[RBINS]; // 32 KB
    int t = threadIdx.x;
    unsigned int bi = blockIdx.x & 31u;  // XCD = bi%8
    unsigned int r  = blockIdx.x >> 5;
    unsigned int r0 = r * RBINS;
    const unsigned int* stg = start + (size_t)bi * START_STRIDE;
    for (int k = t; k < RBINS; k += 1024) cur[k] = stg[r0 + k];
    __syncthreads();
    const uint4* src = (const uint4*)(pixarr + ((size_t)bi << 19));
    unsigned int* dstbase = sorted + (size_t)bi * SORT_STRIDE;
    for (int it = 0; it < 16; it++) {
        uint4 vv[4];
        #pragma unroll
        for (int q = 0; q < 4; q++)
            vv[q] = src[t + (it * 4 + q) * 1024];
        #pragma unroll
        for (int q = 0; q < 4; q++) {
            unsigned int m0 = (t + (it * 4 + q) * 1024) * 8;
            const unsigned int* vw = (const unsigned int*)&vv[q];
            #pragma unroll
            for (int h = 0; h < 8; h++) {
                unsigned int w = vw[h >> 1];
                unsigned int pv = ((h & 1) ? (w >> 16) : (w & 0xFFFFu)) - r0;
                if (pv < RBINS) {
                    unsigned int slot = atomicAdd(&cur[pv], 1u);
                    unsigned int m = m0 + h;                      // (j<<16)|g
                    dstbase[slot] = ((m >> 16) << 27) | (m << 7); // (j<<27)|(rowidx<<7)
                }
            }
        }
    }
    __syncthreads();
    for (int k = t; k < RBINS; k += 1024) {
        unsigned int e = stg[r0 + k + 1];
        for (unsigned int x = cur[k]; x < e; x++) dstbase[x] = SENTINEL;
    }
}

// ---------------- b_gather: explicit 8-wide load batch, launch_bounds(256,4) ----------------
// blockIdx -> (b, gc, i); 8 lanes/row (float4), 8 rows/wave; wave-local MFMA epilogue.
// fv[8] staged before any FMA + 4 waves/EU register budget -> 8 lines in flight per
// lane-group (MLP fix for the 1.3-lines/wave starvation measured in r20).
__global__ __launch_bounds__(256, 4) void b_gather(
    const float* __restrict__ feat,
    const unsigned short* __restrict__ pixarr,
    const unsigned int* __restrict__ start,
    const unsigned int* __restrict__ sorted,
    const float* __restrict__ Wlin,
    const float* __restrict__ blin,
    const float* __restrict__ At,
    float* __restrict__ out)
{
    __shared__ float At9[NBI][16];     // 9-wide weight rows (index 8 = 0.0)
    int t = threadIdx.x;
    int c4 = t & 7;                    // channel quad index
    int grp = t >> 3;                  // 0..31 = row within block

    unsigned int bidx = blockIdx.x;
    unsigned int b  = bidx >> 14;          // 16384 blocks per b
    unsigned int i  = bidx & 7u;           // XCD-pinned view
    unsigned int gc = (bidx >> 3) & 2047u; // g-chunk
    unsigned int bi = (b << 3) | i;
    unsigned int g0 = gc << 5;             // 32 rows per block
    unsigned int g = g0 + grp;
    unsigned int pix = pixarr[(((bi << 3) | i) << 16) | g];

    At9[t >> 3][t & 7] = At[t];
    At9[t >> 3][8 + (t & 7)] = 0.f;

    // preload W fragments (L2-hot, uniform)
    int l = t & 63;
    short8 bf0, bf1;
    #pragma unroll
    for (int j = 0; j < 8; j++) {
        int kk = (l >> 4) * 8 + j;
        bf0[j] = (short)f2bf(Wlin[kk * NC + (l & 15)]);
        bf1[j] = (short)f2bf(Wlin[kk * NC + 16 + (l & 15)]);
    }

    const unsigned int* st = start + (size_t)bi * START_STRIDE;
    unsigned int s0 = st[pix];
    unsigned int e0 = st[pix + 1];
    const unsigned int* pl = sorted + (size_t)bi * SORT_STRIDE;
    const char* fbB = (const char*)(feat + (((size_t)b) << 19) * NC);
    unsigned int cb = c4 << 4;         // float4 byte offset within 128B row
    __syncthreads();

    const float* Atrow = At9[bi];
    float ax = 0.f, ay = 0.f, az = 0.f, aw = 0.f, wsum = 0.f;
    for (unsigned int k0 = s0; k0 < e0; k0 += 8) {
        u32x4 pa = __builtin_nontemporal_load((const u32x4*)(pl + k0));
        u32x4 pb = __builtin_nontemporal_load((const u32x4*)(pl + k0 + 4));
        unsigned int pv[8] = {pa.x, pa.y, pa.z, pa.w, pb.x, pb.y, pb.z, pb.w};
        float4 fv[8];
        #pragma unroll
        for (int h = 0; h < 8; h++)
            fv[h] = *(const float4*)(fbB + ((pv[h] & 0x03FFFF80u) | cb));
        float wv[8];
        #pragma unroll
        for (int h = 0; h < 8; h++)
            wv[h] = Atrow[pv[h] >> 27];
        #pragma unroll
        for (int h = 0; h < 8; h++) {
            ax = fmaf(wv[h], fv[h].x, ax);
            ay = fmaf(wv[h], fv[h].y, ay);
            az = fmaf(wv[h], fv[h].z, az);
            aw = fmaf(wv[h], fv[h].w, aw);
            wsum += wv[h];
        }
    }

    // ---- wave-local MFMA epilogue (no LDS, no barrier); 8 rows per wave ----
    int r = l & 15;
    int kb = l >> 4;
    int s0l = (((r & 7) << 3) | (kb << 1)) & 63;  // j=0..3 source lane
    int s1l = s0l | 1;                            // j=4..7 source lane
    float v0x = __shfl(ax, s0l, 64), v0y = __shfl(ay, s0l, 64);
    float v0z = __shfl(az, s0l, 64), v0w = __shfl(aw, s0l, 64);
    float v1x = __shfl(ax, s1l, 64), v1y = __shfl(ay, s1l, 64);
    float v1z = __shfl(az, s1l, 64), v1w = __shfl(aw, s1l, 64);
    short8 af;
    if (r < 8) {
        af[0] = (short)f2bf(v0x); af[1] = (short)f2bf(v0y);
        af[2] = (short)f2bf(v0z); af[3] = (short)f2bf(v0w);
        af[4] = (short)f2bf(v1x); af[5] = (short)f2bf(v1y);
        af[6] = (short)f2bf(v1z); af[7] = (short)f2bf(v1w);
    } else {
        af = short8{0, 0, 0, 0, 0, 0, 0, 0};
    }
    float bias0 = blin[l & 15];
    float bias1 = blin[16 + (l & 15)];
    f32x4 c0, c1;
    #pragma unroll
    for (int q = 0; q < 4; q++) {
        int row = kb * 4 + q;                       // C/D row for reg q
        float wv = __shfl(wsum, (row << 3) & 63, 64);
        wv = (row < 8) ? wv : 0.f;
        c0[q] = bias0 * wv;
        c1[q] = bias1 * wv;
    }
    c0 = __builtin_amdgcn_mfma_f32_16x16x32_bf16(af, bf0, c0, 0, 0, 0);
    c1 = __builtin_amdgcn_mfma_f32_16x16x32_bf16(af, bf1, c1, 0, 0, 0);
    if (l < 32) {
        size_t rowbase = (((size_t)bi << 16) | g0) + (t >> 6) * 8; // wave's 8 rows
        #pragma unroll
        for (int q = 0; q < 4; q++) {
            size_t rr = rowbase + (l >> 4) * 4 + q;  // rows 0-7 across lanes 0-31
            __builtin_nontemporal_store(c0[q], &out[rr * NC + (l & 15)]);
            __builtin_nontemporal_store(c1[q], &out[rr * NC + 16 + (l & 15)]);
        }
    }
}

extern "C" void kernel_launch(void* const* d_in, const int* in_sizes, int n_in,
                              void* d_out, int out_size, void* d_ws, size_t ws_size,
                              hipStream_t stream)
{
    const float* features = (const float*)d_in[0];
    const float* xy       = (const float*)d_in[1];
    const float* ext      = (const float*)d_in[2];
    const float* Wlin     = (const float*)d_in[3];
    const float* blin     = (const float*)d_in[4];
    float* out = (float*)d_out;

    char* ws = (char*)d_ws;
    float*          At     = (float*)(ws + OFF_AT);
    unsigned int*   rtot   = (unsigned int*)(ws + OFF_RTOT);
    unsigned int*   rbase  = (unsigned int*)(ws + OFF_RBASE);
    unsigned int*   start  = (unsigned int*)(ws + OFF_START);
    unsigned int*   cnt    = (unsigned int*)(ws + OFF_CNT);
    unsigned short* pixarr = (unsigned short*)(ws + OFF_PIX);
    unsigned int*   sorted = (unsigned int*)(ws + OFF_SORT);

    adj_kernel<<<1, 256, 0, stream>>>(ext, out + STACKED_ELEMS, At);

    k1_pix<<<(NB * NV * NV * NG) / 1024, 256, 0, stream>>>((const float2*)xy, pixarr);
    k2_hist<<<NBI * RSPLIT, 1024, 0, stream>>>(pixarr, cnt, rtot);
    k3b_rscan<<<1, 64, 0, stream>>>(rtot, rbase);
    k3c_scan<<<NBI * RSPLIT, 1024, 0, stream>>>(cnt, rbase, start);
    k4_fill<<<NBI * RSPLIT, 1024, 0, stream>>>(pixarr, start, sorted);

    const int nrows_blocks = (NB * NV * NG) / 32; // 65536 blocks x 32 rows
    b_gather<<<nrows_blocks, 256, 0, stream>>>(features, pixarr, start, sorted,
                                               Wlin, blin, At, out);
}